// Round 3
// baseline (2301.319 us; speedup 1.0000x reference)
//
#include <hip/hip_runtime.h>
#include <hip/hip_bf16.h>
#include <math.h>

// MambaBlock: N_EMBD=1024, EXPAND=2 -> D_INNER=2048, D_STATE=16, D_CONV=4,
// DT_RANK=1, B=4, L=2048.
#define SEQLEN 2048
#define NROWS  8192            // B * L
#define DIN    2048            // d_inner
#define DPROJ  33              // dt_rank + 2*d_state

typedef __attribute__((ext_vector_type(8))) short short8;   // 8 bf16 (4 VGPRs)
typedef __attribute__((ext_vector_type(4))) float floatx4;  // MFMA accumulator

__device__ __forceinline__ float silu_f(float z) { return z / (1.f + __expf(-z)); }

// async global->LDS, 16 B per lane. LDS dest must be wave-uniform base; lane i
// lands at base + i*16 (guide §5 caveat m104/m108).
__device__ __forceinline__ void gld_lds16(const void* gptr, void* lptr) {
  __builtin_amdgcn_global_load_lds((__attribute__((address_space(1))) unsigned int*)gptr,
                                   (__attribute__((address_space(3))) unsigned int*)lptr,
                                   16, 0, 0);
}

// ---------------------------------------------------------------------------
// bf16 MFMA GEMM (m97 structure): C[M][N] f32 = A[M][K] bf16 (row-major)
//   x Bt[N][K] bf16 (i.e. B transposed, row-major along K).
// 128x128 block tile, BK=64, 256 threads = 4 waves in 2x2, each wave 64x64.
// M,N % 128 == 0, K % 64 == 0.
// ---------------------------------------------------------------------------
__global__ __launch_bounds__(256) void gemm_bf16(const __hip_bfloat16* __restrict__ A,
                                                 const __hip_bfloat16* __restrict__ Bt,
                                                 float* __restrict__ C,
                                                 int M, int N, int K) {
  __shared__ unsigned short As[128 * 64];  // [r][k], 16 KB
  __shared__ unsigned short Bs[128 * 64];  // [n][k], 16 KB
  const int tid  = threadIdx.x;
  const int lane = tid & 63;
  const int quad = lane >> 4;
  const int l15  = lane & 15;
  const int wv   = tid >> 6;     // wave 0..3
  const int wm   = wv >> 1;      // wave row (0..1)
  const int wn   = wv & 1;       // wave col (0..1)
  const int row0 = blockIdx.y * 128;
  const int col0 = blockIdx.x * 128;

  floatx4 acc[4][4] = {};

  for (int k0 = 0; k0 < K; k0 += 64) {
    // Stage A-tile and Bt-tile: 128 rows x 64 bf16 = 1024 chunks of 16 B each.
    // chunk c = tid + i*256: row = c>>3, k-sub = (c&7)*8. LDS offset = c*16.
#pragma unroll
    for (int i = 0; i < 4; i++) {
      int c = tid + i * 256;
      int r = c >> 3, cc = c & 7;
      gld_lds16(A + (size_t)(row0 + r) * K + k0 + cc * 8,
                (char*)As + (size_t)(i * 256 + wv * 64) * 16);
      gld_lds16(Bt + (size_t)(col0 + r) * K + k0 + cc * 8,
                (char*)Bs + (size_t)(i * 256 + wv * 64) * 16);
    }
    __syncthreads();
#pragma unroll
    for (int ks = 0; ks < 64; ks += 32) {
      short8 a[4], b[4];
#pragma unroll
      for (int t = 0; t < 4; t++) {
        a[t] = *(const short8*)&As[(wm * 64 + t * 16 + l15) * 64 + ks + quad * 8];
        b[t] = *(const short8*)&Bs[(wn * 64 + t * 16 + l15) * 64 + ks + quad * 8];
      }
#pragma unroll
      for (int tm = 0; tm < 4; tm++)
#pragma unroll
        for (int tn = 0; tn < 4; tn++)
          acc[tm][tn] = __builtin_amdgcn_mfma_f32_16x16x32_bf16(a[tm], b[tn], acc[tm][tn], 0, 0, 0);
    }
    __syncthreads();
  }
  // Epilogue: C/D layout col=lane&15, row=quad*4+reg (guide §3, m89-verified).
#pragma unroll
  for (int tm = 0; tm < 4; tm++) {
    int rbase = row0 + wm * 64 + tm * 16 + quad * 4;
#pragma unroll
    for (int tn = 0; tn < 4; tn++) {
      int col = col0 + wn * 64 + tn * 16 + l15;
#pragma unroll
      for (int r = 0; r < 4; r++)
        C[(size_t)(rbase + r) * N + col] = acc[tm][tn][r];
    }
  }
}

// ---------------------------------------------------------------------------
// fp32 -> bf16 elementwise convert (n % 1024 == 0).
// ---------------------------------------------------------------------------
__global__ __launch_bounds__(256) void convert_bf16(const float* __restrict__ in,
                                                    __hip_bfloat16* __restrict__ out,
                                                    int n) {
  int i = (blockIdx.x * 256 + threadIdx.x) * 4;
  if (i >= n) return;
  float4 v = *reinterpret_cast<const float4*>(in + i);
  out[i + 0] = __float2bfloat16(v.x);
  out[i + 1] = __float2bfloat16(v.y);
  out[i + 2] = __float2bfloat16(v.z);
  out[i + 3] = __float2bfloat16(v.w);
}

// ---------------------------------------------------------------------------
// Transpose + convert: w[K][N] f32 -> wt[N][K] bf16. 32x32 LDS tiles.
// ---------------------------------------------------------------------------
__global__ __launch_bounds__(256) void transpose_bf16(const float* __restrict__ w,
                                                      __hip_bfloat16* __restrict__ wt,
                                                      int K, int N) {
  __shared__ float tile[32][33];
  int n0 = blockIdx.x * 32, k0 = blockIdx.y * 32;
  int tx = threadIdx.x;  // 0..31
#pragma unroll
  for (int i = threadIdx.y; i < 32; i += 8)
    tile[i][tx] = w[(size_t)(k0 + i) * N + n0 + tx];
  __syncthreads();
#pragma unroll
  for (int i = threadIdx.y; i < 32; i += 8)
    wt[(size_t)(n0 + i) * K + k0 + tx] = __float2bfloat16(tile[tx][i]);
}

// ---------------------------------------------------------------------------
// Depthwise causal conv (width 4) + SiLU. xr [NROWS][4096], x_ssm = cols 0..2047.
// ---------------------------------------------------------------------------
__global__ __launch_bounds__(256) void conv_silu_kernel(const float* __restrict__ xr,
                                                        const float* __restrict__ conv_w,
                                                        const float* __restrict__ conv_b,
                                                        float* __restrict__ x_c) {
  int idx = blockIdx.x * blockDim.x + threadIdx.x;
  if (idx >= NROWS * DIN) return;
  int d = idx & (DIN - 1);
  int row = idx >> 11;
  int l = row & (SEQLEN - 1);
  float acc = conv_b[d];
#pragma unroll
  for (int k = 0; k < 4; k++) {
    int ls = l + k - 3;
    if (ls >= 0) acc = fmaf(conv_w[d * 4 + k], xr[(size_t)(row + k - 3) * 4096 + d], acc);
  }
  x_c[idx] = silu_f(acc);
}

// ---------------------------------------------------------------------------
// x_dbl[row][0..32] = x_c[row][:] @ x_proj_w[2048][33].
// ---------------------------------------------------------------------------
__global__ void xdbl_kernel(const float* __restrict__ x_c,
                            const float* __restrict__ x_proj_w,
                            float* __restrict__ x_dbl) {
  int row = blockIdx.x;
  int n = threadIdx.x;   // 0..32
  int s = threadIdx.y;   // 0..7
  const float* xrow = x_c + (size_t)row * DIN;
  float acc = 0.f;
  int k0 = s * 256;
  for (int k = k0; k < k0 + 256; k++) acc = fmaf(xrow[k], x_proj_w[k * DPROJ + n], acc);
  __shared__ float part[8][DPROJ];
  part[s][n] = acc;
  __syncthreads();
  if (s == 0) {
    float r = 0.f;
#pragma unroll
    for (int i = 0; i < 8; i++) r += part[i][n];
    x_dbl[(size_t)row * DPROJ + n] = r;
  }
}

// ---------------------------------------------------------------------------
// Selective scan + D skip + gating. 16 lanes per (b,d) channel, lane n = state.
// Overwrites x_c in place with gated fp32 output (each element touched by
// exactly one wave; load precedes store in program order).
// ---------------------------------------------------------------------------
__global__ __launch_bounds__(256) void scan_kernel(float* __restrict__ x_cy,
                                                   const float* __restrict__ x_dbl,
                                                   const float* __restrict__ xr,
                                                   const float* __restrict__ dt_w,
                                                   const float* __restrict__ dt_b,
                                                   const float* __restrict__ A_log,
                                                   const float* __restrict__ Dp) {
  int g = threadIdx.x >> 4;
  int n = threadIdx.x & 15;
  int ch = blockIdx.x * 16 + g;       // 0..8191
  int b = ch >> 11;
  int d = ch & (DIN - 1);
  float An  = -__expf(A_log[d * 16 + n]);
  float dtw = dt_w[d], dtb = dt_b[d], Dd = Dp[d];
  float h = 0.f;
  int row = b * SEQLEN;
  for (int l = 0; l < SEQLEN; l++, row++) {
    const float* xd = x_dbl + (size_t)row * DPROJ;
    float dlt = xd[0];
    float Bn  = xd[1 + n];
    float Cn  = xd[17 + n];
    float xv  = x_cy[(size_t)row * DIN + d];
    float z = fmaf(dlt, dtw, dtb);
    float delta = (z > 20.f) ? z : log1pf(__expf(z));
    h = fmaf(__expf(delta * An), h, Bn * (delta * xv));
    float y = h * Cn;
    y += __shfl_xor(y, 1, 16);
    y += __shfl_xor(y, 2, 16);
    y += __shfl_xor(y, 4, 16);
    y += __shfl_xor(y, 8, 16);
    if (n == 0) {
      float rv = xr[(size_t)row * 4096 + 2048 + d];
      x_cy[(size_t)row * DIN + d] = (y + Dd * xv) * silu_f(rv);
    }
  }
}

// ---------------------------------------------------------------------------
extern "C" void kernel_launch(void* const* d_in, const int* in_sizes, int n_in,
                              void* d_out, int out_size, void* d_ws, size_t ws_size,
                              hipStream_t stream) {
  const float* x         = (const float*)d_in[0];  // (4,2048,1024)
  const float* in_proj_w = (const float*)d_in[1];  // (1024,4096)
  const float* conv_w    = (const float*)d_in[2];  // (2048,1,4)
  const float* conv_b    = (const float*)d_in[3];  // (2048,)
  const float* x_proj_w  = (const float*)d_in[4];  // (2048,33)
  const float* dt_proj_w = (const float*)d_in[5];  // (1,2048)
  const float* dt_proj_b = (const float*)d_in[6];  // (2048,)
  const float* A_log     = (const float*)d_in[7];  // (2048,16)
  const float* Dp        = (const float*)d_in[8];  // (2048,)
  const float* out_proj_w= (const float*)d_in[9];  // (2048,1024)
  float* out = (float*)d_out;                      // (4,2048,1024)

  // Workspace regions (total 202,407,936 B — identical to the round-1-proven
  // footprint). Live ranges are disjoint where aliased:
  //   A [0, 128 MB):   xr f32 (gemm1 out, dead after scan)
  //                    -> gated bf16 (32 MB, written after scan)
  //   B [128, 192 MB): xb bf16 (16 MB) + wt1 bf16 (8 MB)  (dead after gemm1)
  //                    -> x_c f32 (64 MB, conv out; dead after gated convert)
  //                    -> wt3 bf16 (4 MB, written after x_c dies)
  //   C [192 MB, +1.03 MB): xdbl f32
  char* ws = (char*)d_ws;
  float*          xr    = (float*)ws;                               // 8192*4096 f32
  __hip_bfloat16* gated = (__hip_bfloat16*)ws;                      // 8192*2048 bf16
  char* regB = ws + (size_t)NROWS * 4096 * 4;
  __hip_bfloat16* xb    = (__hip_bfloat16*)regB;                    // 8192*1024 bf16
  __hip_bfloat16* wt1   = (__hip_bfloat16*)(regB + (size_t)NROWS * 1024 * 2); // 4096*1024 bf16
  float*          x_c   = (float*)regB;                             // 8192*2048 f32
  __hip_bfloat16* wt3   = (__hip_bfloat16*)regB;                    // 1024*2048 bf16
  float*          xdbl  = (float*)(regB + (size_t)NROWS * DIN * 4); // 8192*33 f32

  // 0) prologue converts: x -> bf16, in_proj_w -> bf16 transposed [4096][1024]
  convert_bf16<<<(NROWS * 1024) / 1024, 256, 0, stream>>>(x, xb, NROWS * 1024);
  transpose_bf16<<<dim3(4096 / 32, 1024 / 32), dim3(32, 8), 0, stream>>>(in_proj_w, wt1, 1024, 4096);

  // 1) xr = x @ in_proj_w  (8192 x 4096, K=1024), bf16 MFMA
  gemm_bf16<<<dim3(4096 / 128, NROWS / 128), 256, 0, stream>>>(xb, wt1, xr, NROWS, 4096, 1024);

  // 2) depthwise conv + silu -> x_c (overwrites xb/wt1, both dead)
  conv_silu_kernel<<<(NROWS * DIN) / 256, 256, 0, stream>>>(xr, conv_w, conv_b, x_c);

  // 3) x_dbl = x_c @ x_proj_w  (8192 x 33, K=2048)
  xdbl_kernel<<<NROWS, dim3(DPROJ, 8), 0, stream>>>(x_c, x_proj_w, xdbl);

  // 4) selective scan + gating, in-place on x_c. 8192 ch / 16 per block = 512.
  scan_kernel<<<512, 256, 0, stream>>>(x_c, xdbl, xr, dt_proj_w, dt_proj_b, A_log, Dp);

  // 5) gated y -> bf16 into region A (xr now dead)
  convert_bf16<<<(NROWS * DIN) / 1024, 256, 0, stream>>>(x_c, gated, NROWS * DIN);

  // 6) out_proj_w -> bf16 transposed [1024][2048] (x_c now dead)
  transpose_bf16<<<dim3(1024 / 32, 2048 / 32), dim3(32, 8), 0, stream>>>(out_proj_w, wt3, 2048, 1024);

  // 7) out = gated @ out_proj_w  (8192 x 1024, K=2048), bf16 MFMA
  gemm_bf16<<<dim3(1024 / 128, NROWS / 128), 256, 0, stream>>>(gated, wt3, out, NROWS, 1024, 2048);
}

// Round 4
// 1150.650 us; speedup vs baseline: 2.0000x; 2.0000x over previous
//
#include <hip/hip_runtime.h>
#include <hip/hip_bf16.h>
#include <math.h>

// MambaBlock: N_EMBD=1024, EXPAND=2 -> D_INNER=2048, D_STATE=16, D_CONV=4,
// DT_RANK=1, B=4, L=2048.
#define SEQLEN 2048
#define NROWS  8192            // B * L
#define DIN    2048            // d_inner

typedef __attribute__((ext_vector_type(8))) short short8;   // 8 bf16 (4 VGPRs)
typedef __attribute__((ext_vector_type(4))) float floatx4;  // MFMA accumulator

__device__ __forceinline__ float silu_f(float z) { return z / (1.f + __expf(-z)); }

// async global->LDS, 16 B per lane (wave-uniform base + lane*16).
__device__ __forceinline__ void gld_lds16(const void* gptr, void* lptr) {
  __builtin_amdgcn_global_load_lds((__attribute__((address_space(1))) unsigned int*)gptr,
                                   (__attribute__((address_space(3))) unsigned int*)lptr,
                                   16, 0, 0);
}

// ---------------------------------------------------------------------------
// bf16 MFMA GEMM (m97 structure): C = A[M][K] x Bt[N][K]^T, fp32 out.
// 128x128 tile, BK=64, 256 threads = 4 waves (2x2), each wave 64x64.
// If Cgate != nullptr: output is split at N/2 — cols [0,N/2) -> C (ld N/2),
// cols [N/2,N) -> silu(acc) into Cgate (ld N/2). Else plain C with ld N.
// ---------------------------------------------------------------------------
__global__ __launch_bounds__(256) void gemm_bf16(const __hip_bfloat16* __restrict__ A,
                                                 const __hip_bfloat16* __restrict__ Bt,
                                                 float* __restrict__ C,
                                                 float* __restrict__ Cgate,
                                                 int M, int N, int K) {
  __shared__ unsigned short As[128 * 64];  // [r][k], 16 KB
  __shared__ unsigned short Bs[128 * 64];  // [n][k], 16 KB
  const int tid  = threadIdx.x;
  const int lane = tid & 63;
  const int quad = lane >> 4;
  const int l15  = lane & 15;
  const int wv   = tid >> 6;
  const int wm   = wv >> 1;
  const int wn   = wv & 1;
  const int row0 = blockIdx.y * 128;
  const int col0 = blockIdx.x * 128;

  floatx4 acc[4][4] = {};

  for (int k0 = 0; k0 < K; k0 += 64) {
#pragma unroll
    for (int i = 0; i < 4; i++) {
      int c = tid + i * 256;
      int r = c >> 3, cc = c & 7;
      gld_lds16(A + (size_t)(row0 + r) * K + k0 + cc * 8,
                (char*)As + (size_t)(i * 256 + wv * 64) * 16);
      gld_lds16(Bt + (size_t)(col0 + r) * K + k0 + cc * 8,
                (char*)Bs + (size_t)(i * 256 + wv * 64) * 16);
    }
    __syncthreads();
#pragma unroll
    for (int ks = 0; ks < 64; ks += 32) {
      short8 a[4], b[4];
#pragma unroll
      for (int t = 0; t < 4; t++) {
        a[t] = *(const short8*)&As[(wm * 64 + t * 16 + l15) * 64 + ks + quad * 8];
        b[t] = *(const short8*)&Bs[(wn * 64 + t * 16 + l15) * 64 + ks + quad * 8];
      }
#pragma unroll
      for (int tm = 0; tm < 4; tm++)
#pragma unroll
        for (int tn = 0; tn < 4; tn++)
          acc[tm][tn] = __builtin_amdgcn_mfma_f32_16x16x32_bf16(a[tm], b[tn], acc[tm][tn], 0, 0, 0);
    }
    __syncthreads();
  }
  // C/D layout: col = lane&15, row = quad*4 + reg.
  const int Nh = N >> 1;
#pragma unroll
  for (int tm = 0; tm < 4; tm++) {
    int rbase = row0 + wm * 64 + tm * 16 + quad * 4;
#pragma unroll
    for (int tn = 0; tn < 4; tn++) {
      int col = col0 + wn * 64 + tn * 16 + l15;
#pragma unroll
      for (int r = 0; r < 4; r++) {
        float v = acc[tm][tn][r];
        if (Cgate) {
          if (col < Nh) C[(size_t)(rbase + r) * Nh + col] = v;
          else          Cgate[(size_t)(rbase + r) * Nh + col - Nh] = silu_f(v);
        } else {
          C[(size_t)(rbase + r) * N + col] = v;
        }
      }
    }
  }
}

// ---------------------------------------------------------------------------
// fp32 -> bf16 convert (n % 1024 == 0).
// ---------------------------------------------------------------------------
__global__ __launch_bounds__(256) void convert_bf16(const float* __restrict__ in,
                                                    __hip_bfloat16* __restrict__ out,
                                                    int n) {
  int i = (blockIdx.x * 256 + threadIdx.x) * 4;
  if (i >= n) return;
  float4 v = *reinterpret_cast<const float4*>(in + i);
  out[i + 0] = __float2bfloat16(v.x);
  out[i + 1] = __float2bfloat16(v.y);
  out[i + 2] = __float2bfloat16(v.z);
  out[i + 3] = __float2bfloat16(v.w);
}

// ---------------------------------------------------------------------------
// gated convert: out_bf16[i] = bf16(yraw[i] * gate[i])   (gate = silu(res))
// ---------------------------------------------------------------------------
__global__ __launch_bounds__(256) void gate_convert_bf16(const float* __restrict__ yraw,
                                                         const float* __restrict__ gate,
                                                         __hip_bfloat16* __restrict__ out,
                                                         int n) {
  int i = (blockIdx.x * 256 + threadIdx.x) * 4;
  if (i >= n) return;
  float4 y = *reinterpret_cast<const float4*>(yraw + i);
  float4 g = *reinterpret_cast<const float4*>(gate + i);
  out[i + 0] = __float2bfloat16(y.x * g.x);
  out[i + 1] = __float2bfloat16(y.y * g.y);
  out[i + 2] = __float2bfloat16(y.z * g.z);
  out[i + 3] = __float2bfloat16(y.w * g.w);
}

// ---------------------------------------------------------------------------
// Transpose + convert: w[K][N] f32 -> wt[N][K] bf16. 32x32 LDS tiles.
// ---------------------------------------------------------------------------
__global__ __launch_bounds__(256) void transpose_bf16(const float* __restrict__ w,
                                                      __hip_bfloat16* __restrict__ wt,
                                                      int K, int N) {
  __shared__ float tile[32][33];
  int n0 = blockIdx.x * 32, k0 = blockIdx.y * 32;
  int tx = threadIdx.x;
#pragma unroll
  for (int i = threadIdx.y; i < 32; i += 8)
    tile[i][tx] = w[(size_t)(k0 + i) * N + n0 + tx];
  __syncthreads();
#pragma unroll
  for (int i = threadIdx.y; i < 32; i += 8)
    wt[(size_t)(n0 + i) * K + k0 + tx] = __float2bfloat16(tile[tx][i]);
}

// ---------------------------------------------------------------------------
// Depthwise causal conv (width 4) + SiLU. xssm [NROWS][2048] -> x_c [NROWS][2048].
// ---------------------------------------------------------------------------
__global__ __launch_bounds__(256) void conv_silu_kernel(const float* __restrict__ xssm,
                                                        const float* __restrict__ conv_w,
                                                        const float* __restrict__ conv_b,
                                                        float* __restrict__ x_c) {
  int idx = blockIdx.x * blockDim.x + threadIdx.x;
  if (idx >= NROWS * DIN) return;
  int d = idx & (DIN - 1);
  int row = idx >> 11;
  int l = row & (SEQLEN - 1);
  float acc = conv_b[d];
#pragma unroll
  for (int k = 0; k < 4; k++) {
    int ls = l + k - 3;
    if (ls >= 0) acc = fmaf(conv_w[d * 4 + k], xssm[(size_t)(row + k - 3) * DIN + d], acc);
  }
  x_c[idx] = silu_f(acc);
}

// ---------------------------------------------------------------------------
// x_proj: for each row, [dlt | B[16] | C[16]] = x_c[row][:] @ x_proj_w[2048][33],
// written to split aligned arrays dlt[NROWS], Bm[NROWS][16], Cm[NROWS][16].
// ---------------------------------------------------------------------------
__global__ void xdbl_kernel(const float* __restrict__ x_c,
                            const float* __restrict__ x_proj_w,
                            float* __restrict__ dlt,
                            float* __restrict__ Bm,
                            float* __restrict__ Cm) {
  int row = blockIdx.x;
  int n = threadIdx.x;   // 0..32
  int s = threadIdx.y;   // 0..7
  const float* xrow = x_c + (size_t)row * DIN;
  float acc = 0.f;
  int k0 = s * 256;
  for (int k = k0; k < k0 + 256; k++) acc = fmaf(xrow[k], x_proj_w[k * 33 + n], acc);
  __shared__ float part[8][33];
  part[s][n] = acc;
  __syncthreads();
  if (s == 0) {
    float r = 0.f;
#pragma unroll
    for (int i = 0; i < 8; i++) r += part[i][n];
    if (n == 0)       dlt[row] = r;
    else if (n <= 16) Bm[(size_t)row * 16 + (n - 1)] = r;
    else              Cm[(size_t)row * 16 + (n - 17)] = r;
  }
}

// ---------------------------------------------------------------------------
// Selective scan, 4 lanes per channel (each lane owns 4 states in registers).
// 512 blocks x 64 threads: block = 16 channels x 4 state-groups, all same batch.
// lane = q*16 + c; q = state group, c = channel-in-block. Distance-1 register
// prefetch of next step's delta/B/C/x. In-place: x_cy read then overwritten
// with y + D*x (gating applied later in gate_convert_bf16).
// ---------------------------------------------------------------------------
__global__ __launch_bounds__(64) void scan4_kernel(float* __restrict__ x_cy,
                                                   const float* __restrict__ dlt,
                                                   const float* __restrict__ Bm,
                                                   const float* __restrict__ Cm,
                                                   const float* __restrict__ dt_w,
                                                   const float* __restrict__ dt_b,
                                                   const float* __restrict__ A_log,
                                                   const float* __restrict__ Dp) {
  const int lane = threadIdx.x;
  const int q = lane >> 4;            // 0..3
  const int c = lane & 15;
  const int ch = blockIdx.x * 16 + c; // 0..8191
  const int b = ch >> 11;
  const int d = ch & (DIN - 1);
  const float dtw = dt_w[d], dtb = dt_b[d], Dd = Dp[d];
  float4 al = *reinterpret_cast<const float4*>(&A_log[d * 16 + q * 4]);
  const float An0 = -__expf(al.x), An1 = -__expf(al.y),
              An2 = -__expf(al.z), An3 = -__expf(al.w);
  float h0 = 0.f, h1 = 0.f, h2 = 0.f, h3 = 0.f;
  int row = b * SEQLEN;
  // prefetch step 0
  float dl = dlt[row];
  float xv = x_cy[(size_t)row * DIN + d];
  float4 B4 = *reinterpret_cast<const float4*>(&Bm[(size_t)row * 16 + q * 4]);
  float4 C4 = *reinterpret_cast<const float4*>(&Cm[(size_t)row * 16 + q * 4]);
  for (int l = 0; l < SEQLEN; l++, row++) {
    // prefetch step l+1 (clamped on the last step; value unused)
    int rn = row + (l < SEQLEN - 1 ? 1 : 0);
    float dl_n = dlt[rn];
    float xv_n = x_cy[(size_t)rn * DIN + d];
    float4 B4n = *reinterpret_cast<const float4*>(&Bm[(size_t)rn * 16 + q * 4]);
    float4 C4n = *reinterpret_cast<const float4*>(&Cm[(size_t)rn * 16 + q * 4]);
    // softplus (|z| << 1 here; branch-free fast path)
    float z = fmaf(dl, dtw, dtb);
    float delta = __logf(1.f + __expf(z));
    float dx = delta * xv;
    h0 = fmaf(__expf(delta * An0), h0, B4.x * dx);
    h1 = fmaf(__expf(delta * An1), h1, B4.y * dx);
    h2 = fmaf(__expf(delta * An2), h2, B4.z * dx);
    h3 = fmaf(__expf(delta * An3), h3, B4.w * dx);
    float y = fmaf(h0, C4.x, fmaf(h1, C4.y, fmaf(h2, C4.z, h3 * C4.w)));
    y += __shfl_xor(y, 16);
    y += __shfl_xor(y, 32);
    if (q == 0) x_cy[(size_t)row * DIN + d] = fmaf(Dd, xv, y);
    dl = dl_n; xv = xv_n; B4 = B4n; C4 = C4n;
  }
}

// ---------------------------------------------------------------------------
extern "C" void kernel_launch(void* const* d_in, const int* in_sizes, int n_in,
                              void* d_out, int out_size, void* d_ws, size_t ws_size,
                              hipStream_t stream) {
  const float* x         = (const float*)d_in[0];  // (4,2048,1024)
  const float* in_proj_w = (const float*)d_in[1];  // (1024,4096)
  const float* conv_w    = (const float*)d_in[2];  // (2048,1,4)
  const float* conv_b    = (const float*)d_in[3];  // (2048,)
  const float* x_proj_w  = (const float*)d_in[4];  // (2048,33)
  const float* dt_proj_w = (const float*)d_in[5];  // (1,2048)
  const float* dt_proj_b = (const float*)d_in[6];  // (2048,)
  const float* A_log     = (const float*)d_in[7];  // (2048,16)
  const float* Dp        = (const float*)d_in[8];  // (2048,)
  const float* out_proj_w= (const float*)d_in[9];  // (2048,1024)
  float* out = (float*)d_out;                      // (4,2048,1024)

  // Workspace regions (total exactly 202,407,936 B):
  //  R0 [0,64M):        xssm f32 (gemm1 lower half; dead after conv)
  //                     -> gated bf16 (32MB @0) + wt3 bf16 (4MB @40MiB)
  //  R1 [64M,128M):     gate f32 = silu(res) (gemm1 upper half; read at step 7)
  //  R2 [128M,192M):    xb bf16 (16MB) + wt1 bf16 (8MB) (dead after gemm1)
  //                     -> x_c f32 (conv out; scan in-place; read at step 7)
  //  R3 [192M,+1.03M):  dlt f32 32KB | Bm f32 512KB | Cm f32 512KB
  char* ws = (char*)d_ws;
  float*          xssm  = (float*)ws;                              // R0
  __hip_bfloat16* gated = (__hip_bfloat16*)ws;                     // R0 @0
  __hip_bfloat16* wt3   = (__hip_bfloat16*)(ws + 41943040);        // R0 @40MiB
  float*          gate  = (float*)(ws + 67108864);                 // R1
  char* regB = ws + 134217728;                                     // R2
  __hip_bfloat16* xb    = (__hip_bfloat16*)regB;
  __hip_bfloat16* wt1   = (__hip_bfloat16*)(regB + (size_t)NROWS * 1024 * 2);
  float*          x_c   = (float*)regB;
  char* regC = ws + 201326592;                                     // R3
  float* dlt = (float*)regC;                                       // 8192
  float* Bm  = (float*)(regC + 32768);                             // 8192*16
  float* Cm  = (float*)(regC + 32768 + 524288);                    // 8192*16

  // 0) prologue: x -> bf16; in_proj_w -> bf16 transposed [4096][1024]
  convert_bf16<<<(NROWS * 1024) / 1024, 256, 0, stream>>>(x, xb, NROWS * 1024);
  transpose_bf16<<<dim3(4096 / 32, 1024 / 32), dim3(32, 8), 0, stream>>>(in_proj_w, wt1, 1024, 4096);

  // 1) gemm1: [xssm | silu(res)->gate] = x @ in_proj_w (8192x4096, K=1024)
  gemm_bf16<<<dim3(4096 / 128, NROWS / 128), 256, 0, stream>>>(xb, wt1, xssm, gate, NROWS, 4096, 1024);

  // 2) depthwise conv + silu -> x_c (overwrites xb/wt1, dead)
  conv_silu_kernel<<<(NROWS * DIN) / 256, 256, 0, stream>>>(xssm, conv_w, conv_b, x_c);

  // 3) x_proj -> dlt, Bm, Cm
  xdbl_kernel<<<NROWS, dim3(33, 8), 0, stream>>>(x_c, x_proj_w, dlt, Bm, Cm);

  // 4) selective scan, in-place on x_c (stores y + D*x, ungated)
  scan4_kernel<<<512, 64, 0, stream>>>(x_c, dlt, Bm, Cm, dt_proj_w, dt_proj_b, A_log, Dp);

  // 5) gated bf16 = bf16(x_c * gate) into R0 (xssm dead)
  gate_convert_bf16<<<(NROWS * DIN) / 1024, 256, 0, stream>>>(x_c, gate, gated, NROWS * DIN);

  // 6) out_proj_w -> bf16 transposed [1024][2048] @ R0+40MiB
  transpose_bf16<<<dim3(1024 / 32, 2048 / 32), dim3(32, 8), 0, stream>>>(out_proj_w, wt3, 2048, 1024);

  // 7) out = gated @ out_proj_w (8192x1024, K=2048)
  gemm_bf16<<<dim3(1024 / 128, NROWS / 128), 256, 0, stream>>>(gated, wt3, out, (float*)nullptr, NROWS, 1024, 2048);
}

// Round 5
// 814.175 us; speedup vs baseline: 2.8266x; 1.4133x over previous
//
#include <hip/hip_runtime.h>
#include <hip/hip_bf16.h>
#include <math.h>

// MambaBlock: N_EMBD=1024, EXPAND=2 -> D_INNER=2048, D_STATE=16, D_CONV=4,
// DT_RANK=1, B=4, L=2048.
#define SEQLEN 2048
#define NROWS  8192            // B * L
#define DIN    2048            // d_inner
#define CHUNK  128             // scan chunk length
#define GCH    16              // SEQLEN / CHUNK

typedef __attribute__((ext_vector_type(8))) short short8;   // 8 bf16 (4 VGPRs)
typedef __attribute__((ext_vector_type(4))) float floatx4;  // MFMA accumulator

__device__ __forceinline__ float silu_f(float z) { return z / (1.f + __expf(-z)); }

// async global->LDS, 16 B per lane (wave-uniform base + lane*16).
__device__ __forceinline__ void gld_lds16(const void* gptr, void* lptr) {
  __builtin_amdgcn_global_load_lds((__attribute__((address_space(1))) unsigned int*)gptr,
                                   (__attribute__((address_space(3))) unsigned int*)lptr,
                                   16, 0, 0);
}

// ---------------------------------------------------------------------------
// bf16 MFMA GEMM (m97 structure): C = A[M][K] x Bt[N][K]^T, fp32 out.
// 128x128 tile, BK=64, 256 threads = 4 waves (2x2), each wave 64x64.
// If Cgate != nullptr: output split at N/2 — cols [0,N/2) -> C (ld N/2),
// cols [N/2,N) -> silu(acc) into Cgate (ld N/2). Else plain C with ld N.
// ---------------------------------------------------------------------------
__global__ __launch_bounds__(256) void gemm_bf16(const __hip_bfloat16* __restrict__ A,
                                                 const __hip_bfloat16* __restrict__ Bt,
                                                 float* __restrict__ C,
                                                 float* __restrict__ Cgate,
                                                 int M, int N, int K) {
  __shared__ unsigned short As[128 * 64];  // [r][k], 16 KB
  __shared__ unsigned short Bs[128 * 64];  // [n][k], 16 KB
  const int tid  = threadIdx.x;
  const int lane = tid & 63;
  const int quad = lane >> 4;
  const int l15  = lane & 15;
  const int wv   = tid >> 6;
  const int wm   = wv >> 1;
  const int wn   = wv & 1;
  const int row0 = blockIdx.y * 128;
  const int col0 = blockIdx.x * 128;

  floatx4 acc[4][4] = {};

  for (int k0 = 0; k0 < K; k0 += 64) {
#pragma unroll
    for (int i = 0; i < 4; i++) {
      int c = tid + i * 256;
      int r = c >> 3, cc = c & 7;
      gld_lds16(A + (size_t)(row0 + r) * K + k0 + cc * 8,
                (char*)As + (size_t)(i * 256 + wv * 64) * 16);
      gld_lds16(Bt + (size_t)(col0 + r) * K + k0 + cc * 8,
                (char*)Bs + (size_t)(i * 256 + wv * 64) * 16);
    }
    __syncthreads();
#pragma unroll
    for (int ks = 0; ks < 64; ks += 32) {
      short8 a[4], b[4];
#pragma unroll
      for (int t = 0; t < 4; t++) {
        a[t] = *(const short8*)&As[(wm * 64 + t * 16 + l15) * 64 + ks + quad * 8];
        b[t] = *(const short8*)&Bs[(wn * 64 + t * 16 + l15) * 64 + ks + quad * 8];
      }
#pragma unroll
      for (int tm = 0; tm < 4; tm++)
#pragma unroll
        for (int tn = 0; tn < 4; tn++)
          acc[tm][tn] = __builtin_amdgcn_mfma_f32_16x16x32_bf16(a[tm], b[tn], acc[tm][tn], 0, 0, 0);
    }
    __syncthreads();
  }
  // C/D layout: col = lane&15, row = quad*4 + reg.
  const int Nh = N >> 1;
#pragma unroll
  for (int tm = 0; tm < 4; tm++) {
    int rbase = row0 + wm * 64 + tm * 16 + quad * 4;
#pragma unroll
    for (int tn = 0; tn < 4; tn++) {
      int col = col0 + wn * 64 + tn * 16 + l15;
#pragma unroll
      for (int r = 0; r < 4; r++) {
        float v = acc[tm][tn][r];
        if (Cgate) {
          if (col < Nh) C[(size_t)(rbase + r) * Nh + col] = v;
          else          Cgate[(size_t)(rbase + r) * Nh + col - Nh] = silu_f(v);
        } else {
          C[(size_t)(rbase + r) * N + col] = v;
        }
      }
    }
  }
}

// ---------------------------------------------------------------------------
// fp32 -> bf16 convert (n % 1024 == 0).
// ---------------------------------------------------------------------------
__global__ __launch_bounds__(256) void convert_bf16(const float* __restrict__ in,
                                                    __hip_bfloat16* __restrict__ out,
                                                    int n) {
  int i = (blockIdx.x * 256 + threadIdx.x) * 4;
  if (i >= n) return;
  float4 v = *reinterpret_cast<const float4*>(in + i);
  out[i + 0] = __float2bfloat16(v.x);
  out[i + 1] = __float2bfloat16(v.y);
  out[i + 2] = __float2bfloat16(v.z);
  out[i + 3] = __float2bfloat16(v.w);
}

// ---------------------------------------------------------------------------
// gated convert: out_bf16[i] = bf16(yraw[i] * gate[i])   (gate = silu(res))
// ---------------------------------------------------------------------------
__global__ __launch_bounds__(256) void gate_convert_bf16(const float* __restrict__ yraw,
                                                         const float* __restrict__ gate,
                                                         __hip_bfloat16* __restrict__ out,
                                                         int n) {
  int i = (blockIdx.x * 256 + threadIdx.x) * 4;
  if (i >= n) return;
  float4 y = *reinterpret_cast<const float4*>(yraw + i);
  float4 g = *reinterpret_cast<const float4*>(gate + i);
  out[i + 0] = __float2bfloat16(y.x * g.x);
  out[i + 1] = __float2bfloat16(y.y * g.y);
  out[i + 2] = __float2bfloat16(y.z * g.z);
  out[i + 3] = __float2bfloat16(y.w * g.w);
}

// ---------------------------------------------------------------------------
// Transpose + convert: w[K][N] f32 -> wt[N][K] bf16. 32x32 LDS tiles.
// ---------------------------------------------------------------------------
__global__ __launch_bounds__(256) void transpose_bf16(const float* __restrict__ w,
                                                      __hip_bfloat16* __restrict__ wt,
                                                      int K, int N) {
  __shared__ float tile[32][33];
  int n0 = blockIdx.x * 32, k0 = blockIdx.y * 32;
  int tx = threadIdx.x;
#pragma unroll
  for (int i = threadIdx.y; i < 32; i += 8)
    tile[i][tx] = w[(size_t)(k0 + i) * N + n0 + tx];
  __syncthreads();
#pragma unroll
  for (int i = threadIdx.y; i < 32; i += 8)
    wt[(size_t)(n0 + i) * K + k0 + tx] = __float2bfloat16(tile[tx][i]);
}

// ---------------------------------------------------------------------------
// Depthwise causal conv (width 4) + SiLU. xssm [NROWS][2048] -> x_c [NROWS][2048].
// ---------------------------------------------------------------------------
__global__ __launch_bounds__(256) void conv_silu_kernel(const float* __restrict__ xssm,
                                                        const float* __restrict__ conv_w,
                                                        const float* __restrict__ conv_b,
                                                        float* __restrict__ x_c) {
  int idx = blockIdx.x * blockDim.x + threadIdx.x;
  if (idx >= NROWS * DIN) return;
  int d = idx & (DIN - 1);
  int row = idx >> 11;
  int l = row & (SEQLEN - 1);
  float acc = conv_b[d];
#pragma unroll
  for (int k = 0; k < 4; k++) {
    int ls = l + k - 3;
    if (ls >= 0) acc = fmaf(conv_w[d * 4 + k], xssm[(size_t)(row + k - 3) * DIN + d], acc);
  }
  x_c[idx] = silu_f(acc);
}

// ---------------------------------------------------------------------------
// x_proj: [dlt | B[16] | C[16]] = x_c[row][:] @ x_proj_w[2048][33], split out.
// ---------------------------------------------------------------------------
__global__ void xdbl_kernel(const float* __restrict__ x_c,
                            const float* __restrict__ x_proj_w,
                            float* __restrict__ dlt,
                            float* __restrict__ Bm,
                            float* __restrict__ Cm) {
  int row = blockIdx.x;
  int n = threadIdx.x;   // 0..32
  int s = threadIdx.y;   // 0..7
  const float* xrow = x_c + (size_t)row * DIN;
  float acc = 0.f;
  int k0 = s * 256;
  for (int k = k0; k < k0 + 256; k++) acc = fmaf(xrow[k], x_proj_w[k * 33 + n], acc);
  __shared__ float part[8][33];
  part[s][n] = acc;
  __syncthreads();
  if (s == 0) {
    float r = 0.f;
#pragma unroll
    for (int i = 0; i < 8; i++) r += part[i][n];
    if (n == 0)       dlt[row] = r;
    else if (n <= 16) Bm[(size_t)row * 16 + (n - 1)] = r;
    else              Cm[(size_t)row * 16 + (n - 17)] = r;
  }
}

// ---------------------------------------------------------------------------
// Chunked selective scan, 3 passes. Mapping (passes A/C): 256-thr block = 4
// waves; wave w handles chunk g = blockIdx.y*4+w for 16 channels; within a
// wave lane = q*16+c (q = state group of 4, c = channel). grid (512, 4).
// ---------------------------------------------------------------------------
__global__ __launch_bounds__(256) void scan_passA(const float* __restrict__ x_c,
                                                  const float* __restrict__ dlt,
                                                  const float* __restrict__ Bm,
                                                  const float* __restrict__ dt_w,
                                                  const float* __restrict__ dt_b,
                                                  const float* __restrict__ A_log,
                                                  float* __restrict__ hend,
                                                  float* __restrict__ sumdelta) {
  const int tid = threadIdx.x;
  const int lane = tid & 63;
  const int q = lane >> 4, c = lane & 15;
  const int g = blockIdx.y * 4 + (tid >> 6);
  const int ch = blockIdx.x * 16 + c;
  const int b = ch >> 11, d = ch & (DIN - 1);
  const float dtw = dt_w[d], dtb = dt_b[d];
  float4 al = *reinterpret_cast<const float4*>(&A_log[d * 16 + q * 4]);
  const float An0 = -__expf(al.x), An1 = -__expf(al.y),
              An2 = -__expf(al.z), An3 = -__expf(al.w);
  float h0 = 0.f, h1 = 0.f, h2 = 0.f, h3 = 0.f, sd = 0.f;
  int row = b * SEQLEN + g * CHUNK;
  float dl = dlt[row];
  float xv = x_c[(size_t)row * DIN + d];
  float4 B4 = *reinterpret_cast<const float4*>(&Bm[(size_t)row * 16 + q * 4]);
  for (int l = 0; l < CHUNK; l++, row++) {
    int rn = row + (l < CHUNK - 1 ? 1 : 0);
    float dl_n = dlt[rn];
    float xv_n = x_c[(size_t)rn * DIN + d];
    float4 B4n = *reinterpret_cast<const float4*>(&Bm[(size_t)rn * 16 + q * 4]);
    float z = fmaf(dl, dtw, dtb);
    float delta = __logf(1.f + __expf(z));
    sd += delta;
    float dx = delta * xv;
    h0 = fmaf(__expf(delta * An0), h0, B4.x * dx);
    h1 = fmaf(__expf(delta * An1), h1, B4.y * dx);
    h2 = fmaf(__expf(delta * An2), h2, B4.z * dx);
    h3 = fmaf(__expf(delta * An3), h3, B4.w * dx);
    dl = dl_n; xv = xv_n; B4 = B4n;
  }
  // hend layout [g][ch][16] for coalescing.
  size_t base = ((size_t)g * 8192 + ch) * 16 + q * 4;
  float4 hv = {h0, h1, h2, h3};
  *reinterpret_cast<float4*>(&hend[base]) = hv;
  if (q == 0) sumdelta[g * 8192 + ch] = sd;
}

// Combine chunk summaries: hinit[g] = exp(A*sumdelta[g-1])*hinit[g-1] + hend[g-1].
__global__ __launch_bounds__(256) void scan_passB(const float* __restrict__ A_log,
                                                  const float* __restrict__ sumdelta,
                                                  const float* __restrict__ hend,
                                                  float* __restrict__ hinit) {
  int t = blockIdx.x * 256 + threadIdx.x;   // 0..32767
  int ch = t >> 2, q = t & 3;
  int d = ch & (DIN - 1);
  float4 al = *reinterpret_cast<const float4*>(&A_log[d * 16 + q * 4]);
  const float An0 = -__expf(al.x), An1 = -__expf(al.y),
              An2 = -__expf(al.z), An3 = -__expf(al.w);
  float4 h = {0.f, 0.f, 0.f, 0.f};
#pragma unroll
  for (int g = 0; g < GCH; g++) {
    size_t base = ((size_t)g * 8192 + ch) * 16 + q * 4;
    *reinterpret_cast<float4*>(&hinit[base]) = h;
    float sd = sumdelta[g * 8192 + ch];
    float4 he = *reinterpret_cast<const float4*>(&hend[base]);
    h.x = fmaf(__expf(An0 * sd), h.x, he.x);
    h.y = fmaf(__expf(An1 * sd), h.y, he.y);
    h.z = fmaf(__expf(An2 * sd), h.z, he.z);
    h.w = fmaf(__expf(An3 * sd), h.w, he.w);
  }
}

__global__ __launch_bounds__(256) void scan_passC(float* __restrict__ x_cy,
                                                  const float* __restrict__ dlt,
                                                  const float* __restrict__ Bm,
                                                  const float* __restrict__ Cm,
                                                  const float* __restrict__ dt_w,
                                                  const float* __restrict__ dt_b,
                                                  const float* __restrict__ A_log,
                                                  const float* __restrict__ Dp,
                                                  const float* __restrict__ hinit) {
  const int tid = threadIdx.x;
  const int lane = tid & 63;
  const int q = lane >> 4, c = lane & 15;
  const int g = blockIdx.y * 4 + (tid >> 6);
  const int ch = blockIdx.x * 16 + c;
  const int b = ch >> 11, d = ch & (DIN - 1);
  const float dtw = dt_w[d], dtb = dt_b[d], Dd = Dp[d];
  float4 al = *reinterpret_cast<const float4*>(&A_log[d * 16 + q * 4]);
  const float An0 = -__expf(al.x), An1 = -__expf(al.y),
              An2 = -__expf(al.z), An3 = -__expf(al.w);
  float4 h4 = *reinterpret_cast<const float4*>(&hinit[((size_t)g * 8192 + ch) * 16 + q * 4]);
  float h0 = h4.x, h1 = h4.y, h2 = h4.z, h3 = h4.w;
  int row = b * SEQLEN + g * CHUNK;
  float dl = dlt[row];
  float xv = x_cy[(size_t)row * DIN + d];
  float4 B4 = *reinterpret_cast<const float4*>(&Bm[(size_t)row * 16 + q * 4]);
  float4 C4 = *reinterpret_cast<const float4*>(&Cm[(size_t)row * 16 + q * 4]);
  for (int l = 0; l < CHUNK; l++, row++) {
    int rn = row + (l < CHUNK - 1 ? 1 : 0);
    float dl_n = dlt[rn];
    float xv_n = x_cy[(size_t)rn * DIN + d];
    float4 B4n = *reinterpret_cast<const float4*>(&Bm[(size_t)rn * 16 + q * 4]);
    float4 C4n = *reinterpret_cast<const float4*>(&Cm[(size_t)rn * 16 + q * 4]);
    float z = fmaf(dl, dtw, dtb);
    float delta = __logf(1.f + __expf(z));
    float dx = delta * xv;
    h0 = fmaf(__expf(delta * An0), h0, B4.x * dx);
    h1 = fmaf(__expf(delta * An1), h1, B4.y * dx);
    h2 = fmaf(__expf(delta * An2), h2, B4.z * dx);
    h3 = fmaf(__expf(delta * An3), h3, B4.w * dx);
    float y = fmaf(h0, C4.x, fmaf(h1, C4.y, fmaf(h2, C4.z, h3 * C4.w)));
    y += __shfl_xor(y, 16);
    y += __shfl_xor(y, 32);
    if (q == 0) x_cy[(size_t)row * DIN + d] = fmaf(Dd, xv, y);
    dl = dl_n; xv = xv_n; B4 = B4n; C4 = C4n;
  }
}

// ---------------------------------------------------------------------------
extern "C" void kernel_launch(void* const* d_in, const int* in_sizes, int n_in,
                              void* d_out, int out_size, void* d_ws, size_t ws_size,
                              hipStream_t stream) {
  const float* x         = (const float*)d_in[0];  // (4,2048,1024)
  const float* in_proj_w = (const float*)d_in[1];  // (1024,4096)
  const float* conv_w    = (const float*)d_in[2];  // (2048,1,4)
  const float* conv_b    = (const float*)d_in[3];  // (2048,)
  const float* x_proj_w  = (const float*)d_in[4];  // (2048,33)
  const float* dt_proj_w = (const float*)d_in[5];  // (1,2048)
  const float* dt_proj_b = (const float*)d_in[6];  // (2048,)
  const float* A_log     = (const float*)d_in[7];  // (2048,16)
  const float* Dp        = (const float*)d_in[8];  // (2048,)
  const float* out_proj_w= (const float*)d_in[9];  // (2048,1024)
  float* out = (float*)d_out;                      // (4,2048,1024)

  // Workspace regions (total exactly 202,407,936 B):
  //  R0 [0,64M):  xssm f32 (gemm1 lower half; dead after conv)
  //               -> scan scratch: hend 8MB @0 | hinit 8MB @8MiB | sumdelta @16MiB
  //               -> gated bf16 (32MB @0) + wt3 bf16 (4MB @40MiB)  [after scan]
  //  R1 [64M,128M):  gate f32 = silu(res) (gemm1 upper half; read at step 5)
  //  R2 [128M,192M): xb bf16 (16MB) + wt1 bf16 (8MB) (dead after gemm1)
  //                  -> x_c f32 (conv out; scan in-place; read at step 5)
  //  R3 [192M,+1.03M): dlt f32 32KB | Bm f32 512KB | Cm f32 512KB
  char* ws = (char*)d_ws;
  float*          xssm  = (float*)ws;                              // R0
  float*          hend  = (float*)ws;                              // R0 @0, 8 MB
  float*          hinit = (float*)(ws + (8u << 20));               // R0 @8MiB, 8 MB
  float*          sumdl = (float*)(ws + (16u << 20));              // R0 @16MiB, 512 KB
  __hip_bfloat16* gated = (__hip_bfloat16*)ws;                     // R0 @0 (after scan)
  __hip_bfloat16* wt3   = (__hip_bfloat16*)(ws + 41943040);        // R0 @40MiB
  float*          gate  = (float*)(ws + 67108864);                 // R1
  char* regB = ws + 134217728;                                     // R2
  __hip_bfloat16* xb    = (__hip_bfloat16*)regB;
  __hip_bfloat16* wt1   = (__hip_bfloat16*)(regB + (size_t)NROWS * 1024 * 2);
  float*          x_c   = (float*)regB;
  char* regC = ws + 201326592;                                     // R3
  float* dlt = (float*)regC;                                       // 8192
  float* Bm  = (float*)(regC + 32768);                             // 8192*16
  float* Cm  = (float*)(regC + 32768 + 524288);                    // 8192*16

  // 0) prologue: x -> bf16; in_proj_w -> bf16 transposed [4096][1024]
  convert_bf16<<<(NROWS * 1024) / 1024, 256, 0, stream>>>(x, xb, NROWS * 1024);
  transpose_bf16<<<dim3(4096 / 32, 1024 / 32), dim3(32, 8), 0, stream>>>(in_proj_w, wt1, 1024, 4096);

  // 1) gemm1: [xssm | silu(res)->gate] = x @ in_proj_w (8192x4096, K=1024)
  gemm_bf16<<<dim3(4096 / 128, NROWS / 128), 256, 0, stream>>>(xb, wt1, xssm, gate, NROWS, 4096, 1024);

  // 2) depthwise conv + silu -> x_c (overwrites xb/wt1, dead)
  conv_silu_kernel<<<(NROWS * DIN) / 256, 256, 0, stream>>>(xssm, conv_w, conv_b, x_c);

  // 3) x_proj -> dlt, Bm, Cm
  xdbl_kernel<<<NROWS, dim3(33, 8), 0, stream>>>(x_c, x_proj_w, dlt, Bm, Cm);

  // 4) chunked selective scan (3 passes), in-place on x_c (stores y + D*x)
  scan_passA<<<dim3(512, GCH / 4), 256, 0, stream>>>(x_c, dlt, Bm, dt_proj_w, dt_proj_b, A_log, hend, sumdl);
  scan_passB<<<128, 256, 0, stream>>>(A_log, sumdl, hend, hinit);
  scan_passC<<<dim3(512, GCH / 4), 256, 0, stream>>>(x_c, dlt, Bm, Cm, dt_proj_w, dt_proj_b, A_log, Dp, hinit);

  // 5) gated bf16 = bf16(x_c * gate) into R0 (scan scratch dead)
  gate_convert_bf16<<<(NROWS * DIN) / 1024, 256, 0, stream>>>(x_c, gate, gated, NROWS * DIN);

  // 6) out_proj_w -> bf16 transposed [1024][2048] @ R0+40MiB
  transpose_bf16<<<dim3(1024 / 32, 2048 / 32), dim3(32, 8), 0, stream>>>(out_proj_w, wt3, 2048, 1024);

  // 7) out = gated @ out_proj_w (8192x1024, K=2048)
  gemm_bf16<<<dim3(1024 / 128, NROWS / 128), 256, 0, stream>>>(gated, wt3, out, (float*)nullptr, NROWS, 1024, 2048);
}

// Round 6
// 639.421 us; speedup vs baseline: 3.5991x; 1.2733x over previous
//
#include <hip/hip_runtime.h>
#include <hip/hip_bf16.h>
#include <math.h>

// MambaBlock: N_EMBD=1024, EXPAND=2 -> D_INNER=2048, D_STATE=16, D_CONV=4,
// DT_RANK=1, B=4, L=2048.
#define SEQLEN 2048
#define NROWS  8192            // B * L
#define DIN    2048            // d_inner
#define CHUNK  128             // scan chunk length
#define GCH    16              // SEQLEN / CHUNK

typedef __attribute__((ext_vector_type(8))) short short8;   // 8 bf16 (4 VGPRs)
typedef __attribute__((ext_vector_type(4))) float floatx4;  // MFMA accumulator

__device__ __forceinline__ float silu_f(float z) { return z / (1.f + __expf(-z)); }

// async global->LDS, 16 B per lane (wave-uniform base + lane*16).
__device__ __forceinline__ void gld_lds16(const void* gptr, void* lptr) {
  __builtin_amdgcn_global_load_lds((__attribute__((address_space(1))) unsigned int*)gptr,
                                   (__attribute__((address_space(3))) unsigned int*)lptr,
                                   16, 0, 0);
}

// ---------------------------------------------------------------------------
// bf16 MFMA GEMM (m97 structure): C = A[M][K] x Bt[N][K]^T, fp32 out.
// 128x128 tile, BK=64, 256 threads = 4 waves (2x2), each wave 64x64.
// If Cgate != nullptr: output split at N/2 — cols [0,N/2) -> C (ld N/2),
// cols [N/2,N) -> silu(acc) into Cgate (ld N/2). Else plain C with ld N.
// ---------------------------------------------------------------------------
__global__ __launch_bounds__(256) void gemm_bf16(const __hip_bfloat16* __restrict__ A,
                                                 const __hip_bfloat16* __restrict__ Bt,
                                                 float* __restrict__ C,
                                                 float* __restrict__ Cgate,
                                                 int M, int N, int K) {
  __shared__ unsigned short As[128 * 64];  // [r][k], 16 KB
  __shared__ unsigned short Bs[128 * 64];  // [n][k], 16 KB
  const int tid  = threadIdx.x;
  const int lane = tid & 63;
  const int quad = lane >> 4;
  const int l15  = lane & 15;
  const int wv   = tid >> 6;
  const int wm   = wv >> 1;
  const int wn   = wv & 1;
  const int row0 = blockIdx.y * 128;
  const int col0 = blockIdx.x * 128;

  floatx4 acc[4][4] = {};

  for (int k0 = 0; k0 < K; k0 += 64) {
#pragma unroll
    for (int i = 0; i < 4; i++) {
      int c = tid + i * 256;
      int r = c >> 3, cc = c & 7;
      gld_lds16(A + (size_t)(row0 + r) * K + k0 + cc * 8,
                (char*)As + (size_t)(i * 256 + wv * 64) * 16);
      gld_lds16(Bt + (size_t)(col0 + r) * K + k0 + cc * 8,
                (char*)Bs + (size_t)(i * 256 + wv * 64) * 16);
    }
    __syncthreads();
#pragma unroll
    for (int ks = 0; ks < 64; ks += 32) {
      short8 a[4], b[4];
#pragma unroll
      for (int t = 0; t < 4; t++) {
        a[t] = *(const short8*)&As[(wm * 64 + t * 16 + l15) * 64 + ks + quad * 8];
        b[t] = *(const short8*)&Bs[(wn * 64 + t * 16 + l15) * 64 + ks + quad * 8];
      }
#pragma unroll
      for (int tm = 0; tm < 4; tm++)
#pragma unroll
        for (int tn = 0; tn < 4; tn++)
          acc[tm][tn] = __builtin_amdgcn_mfma_f32_16x16x32_bf16(a[tm], b[tn], acc[tm][tn], 0, 0, 0);
    }
    __syncthreads();
  }
  // C/D layout: col = lane&15, row = quad*4 + reg.
  const int Nh = N >> 1;
#pragma unroll
  for (int tm = 0; tm < 4; tm++) {
    int rbase = row0 + wm * 64 + tm * 16 + quad * 4;
#pragma unroll
    for (int tn = 0; tn < 4; tn++) {
      int col = col0 + wn * 64 + tn * 16 + l15;
#pragma unroll
      for (int r = 0; r < 4; r++) {
        float v = acc[tm][tn][r];
        if (Cgate) {
          if (col < Nh) C[(size_t)(rbase + r) * Nh + col] = v;
          else          Cgate[(size_t)(rbase + r) * Nh + col - Nh] = silu_f(v);
        } else {
          C[(size_t)(rbase + r) * N + col] = v;
        }
      }
    }
  }
}

// ---------------------------------------------------------------------------
// fp32 -> bf16 convert (n % 1024 == 0).
// ---------------------------------------------------------------------------
__global__ __launch_bounds__(256) void convert_bf16(const float* __restrict__ in,
                                                    __hip_bfloat16* __restrict__ out,
                                                    int n) {
  int i = (blockIdx.x * 256 + threadIdx.x) * 4;
  if (i >= n) return;
  float4 v = *reinterpret_cast<const float4*>(in + i);
  out[i + 0] = __float2bfloat16(v.x);
  out[i + 1] = __float2bfloat16(v.y);
  out[i + 2] = __float2bfloat16(v.z);
  out[i + 3] = __float2bfloat16(v.w);
}

// ---------------------------------------------------------------------------
// gated convert: out_bf16[i] = bf16(yraw[i] * gate[i])   (gate = silu(res))
// ---------------------------------------------------------------------------
__global__ __launch_bounds__(256) void gate_convert_bf16(const float* __restrict__ yraw,
                                                         const float* __restrict__ gate,
                                                         __hip_bfloat16* __restrict__ out,
                                                         int n) {
  int i = (blockIdx.x * 256 + threadIdx.x) * 4;
  if (i >= n) return;
  float4 y = *reinterpret_cast<const float4*>(yraw + i);
  float4 g = *reinterpret_cast<const float4*>(gate + i);
  out[i + 0] = __float2bfloat16(y.x * g.x);
  out[i + 1] = __float2bfloat16(y.y * g.y);
  out[i + 2] = __float2bfloat16(y.z * g.z);
  out[i + 3] = __float2bfloat16(y.w * g.w);
}

// ---------------------------------------------------------------------------
// Transpose + convert: w[K][N] f32 -> wt[N][K] bf16. 32x32 LDS tiles.
// ---------------------------------------------------------------------------
__global__ __launch_bounds__(256) void transpose_bf16(const float* __restrict__ w,
                                                      __hip_bfloat16* __restrict__ wt,
                                                      int K, int N) {
  __shared__ float tile[32][33];
  int n0 = blockIdx.x * 32, k0 = blockIdx.y * 32;
  int tx = threadIdx.x;
#pragma unroll
  for (int i = threadIdx.y; i < 32; i += 8)
    tile[i][tx] = w[(size_t)(k0 + i) * N + n0 + tx];
  __syncthreads();
#pragma unroll
  for (int i = threadIdx.y; i < 32; i += 8)
    wt[(size_t)(n0 + i) * K + k0 + tx] = __float2bfloat16(tile[tx][i]);
}

// ---------------------------------------------------------------------------
// Pack x_proj_w[2048][33] f32 -> wtp[128][2048] bf16 (transposed + padded):
//   wtp row 0      <- W col 0  (delta)
//   wtp rows 4..19 <- W cols 1..16  (B)   } both map to W col (n-3)
//   wtp rows 20..35<- W cols 17..32 (C)   }
//   all other rows zero.
// This row placement keeps the scan's float4 reads 16B-aligned.
// ---------------------------------------------------------------------------
__global__ __launch_bounds__(256) void pack_xproj(const float* __restrict__ w,
                                                  __hip_bfloat16* __restrict__ wtp) {
  int idx = blockIdx.x * 256 + threadIdx.x;   // 0 .. 128*2048-1
  int n = idx >> 11;          // padded row 0..127
  int k = idx & 2047;         // 0..2047
  int src = (n == 0) ? 0 : ((n >= 4 && n < 36) ? (n - 3) : -1);
  float v = (src >= 0) ? w[(size_t)k * 33 + src] : 0.f;
  wtp[idx] = __float2bfloat16(v);
}

// ---------------------------------------------------------------------------
// Depthwise causal conv (width 4) + SiLU. xssm [NROWS][2048] -> x_c [NROWS][2048].
// ---------------------------------------------------------------------------
__global__ __launch_bounds__(256) void conv_silu_kernel(const float* __restrict__ xssm,
                                                        const float* __restrict__ conv_w,
                                                        const float* __restrict__ conv_b,
                                                        float* __restrict__ x_c) {
  int idx = blockIdx.x * blockDim.x + threadIdx.x;
  if (idx >= NROWS * DIN) return;
  int d = idx & (DIN - 1);
  int row = idx >> 11;
  int l = row & (SEQLEN - 1);
  float acc = conv_b[d];
#pragma unroll
  for (int k = 0; k < 4; k++) {
    int ls = l + k - 3;
    if (ls >= 0) acc = fmaf(conv_w[d * 4 + k], xssm[(size_t)(row + k - 3) * DIN + d], acc);
  }
  x_c[idx] = silu_f(acc);
}

// ---------------------------------------------------------------------------
// Chunked selective scan, 3 passes. delta/B/C come from xd = xdbl128[row][128]:
//   dl = xd[row*128], B4 = xd[row*128+4+q*4], C4 = xd[row*128+20+q*4].
// Mapping (passes A/C): 256-thr block = 4 waves; wave w handles chunk
// g = blockIdx.y*4+w for 16 channels; lane = q*16+c. grid (512, 4).
// ---------------------------------------------------------------------------
__global__ __launch_bounds__(256) void scan_passA(const float* __restrict__ x_c,
                                                  const float* __restrict__ xd,
                                                  const float* __restrict__ dt_w,
                                                  const float* __restrict__ dt_b,
                                                  const float* __restrict__ A_log,
                                                  float* __restrict__ hend,
                                                  float* __restrict__ sumdelta) {
  const int tid = threadIdx.x;
  const int lane = tid & 63;
  const int q = lane >> 4, c = lane & 15;
  const int g = blockIdx.y * 4 + (tid >> 6);
  const int ch = blockIdx.x * 16 + c;
  const int b = ch >> 11, d = ch & (DIN - 1);
  const float dtw = dt_w[d], dtb = dt_b[d];
  float4 al = *reinterpret_cast<const float4*>(&A_log[d * 16 + q * 4]);
  const float An0 = -__expf(al.x), An1 = -__expf(al.y),
              An2 = -__expf(al.z), An3 = -__expf(al.w);
  float h0 = 0.f, h1 = 0.f, h2 = 0.f, h3 = 0.f, sd = 0.f;
  int row = b * SEQLEN + g * CHUNK;
  float dl = xd[(size_t)row * 128];
  float xv = x_c[(size_t)row * DIN + d];
  float4 B4 = *reinterpret_cast<const float4*>(&xd[(size_t)row * 128 + 4 + q * 4]);
  for (int l = 0; l < CHUNK; l++, row++) {
    int rn = row + (l < CHUNK - 1 ? 1 : 0);
    float dl_n = xd[(size_t)rn * 128];
    float xv_n = x_c[(size_t)rn * DIN + d];
    float4 B4n = *reinterpret_cast<const float4*>(&xd[(size_t)rn * 128 + 4 + q * 4]);
    float z = fmaf(dl, dtw, dtb);
    float delta = __logf(1.f + __expf(z));
    sd += delta;
    float dx = delta * xv;
    h0 = fmaf(__expf(delta * An0), h0, B4.x * dx);
    h1 = fmaf(__expf(delta * An1), h1, B4.y * dx);
    h2 = fmaf(__expf(delta * An2), h2, B4.z * dx);
    h3 = fmaf(__expf(delta * An3), h3, B4.w * dx);
    dl = dl_n; xv = xv_n; B4 = B4n;
  }
  // hend layout [g][ch][16] for coalescing.
  size_t base = ((size_t)g * 8192 + ch) * 16 + q * 4;
  float4 hv = {h0, h1, h2, h3};
  *reinterpret_cast<float4*>(&hend[base]) = hv;
  if (q == 0) sumdelta[g * 8192 + ch] = sd;
}

// Combine chunk summaries: hinit[g] = exp(A*sumdelta[g-1])*hinit[g-1] + hend[g-1].
__global__ __launch_bounds__(256) void scan_passB(const float* __restrict__ A_log,
                                                  const float* __restrict__ sumdelta,
                                                  const float* __restrict__ hend,
                                                  float* __restrict__ hinit) {
  int t = blockIdx.x * 256 + threadIdx.x;   // 0..32767
  int ch = t >> 2, q = t & 3;
  int d = ch & (DIN - 1);
  float4 al = *reinterpret_cast<const float4*>(&A_log[d * 16 + q * 4]);
  const float An0 = -__expf(al.x), An1 = -__expf(al.y),
              An2 = -__expf(al.z), An3 = -__expf(al.w);
  float4 h = {0.f, 0.f, 0.f, 0.f};
#pragma unroll
  for (int g = 0; g < GCH; g++) {
    size_t base = ((size_t)g * 8192 + ch) * 16 + q * 4;
    *reinterpret_cast<float4*>(&hinit[base]) = h;
    float sd = sumdelta[g * 8192 + ch];
    float4 he = *reinterpret_cast<const float4*>(&hend[base]);
    h.x = fmaf(__expf(An0 * sd), h.x, he.x);
    h.y = fmaf(__expf(An1 * sd), h.y, he.y);
    h.z = fmaf(__expf(An2 * sd), h.z, he.z);
    h.w = fmaf(__expf(An3 * sd), h.w, he.w);
  }
}

__global__ __launch_bounds__(256) void scan_passC(float* __restrict__ x_cy,
                                                  const float* __restrict__ xd,
                                                  const float* __restrict__ dt_w,
                                                  const float* __restrict__ dt_b,
                                                  const float* __restrict__ A_log,
                                                  const float* __restrict__ Dp,
                                                  const float* __restrict__ hinit) {
  const int tid = threadIdx.x;
  const int lane = tid & 63;
  const int q = lane >> 4, c = lane & 15;
  const int g = blockIdx.y * 4 + (tid >> 6);
  const int ch = blockIdx.x * 16 + c;
  const int b = ch >> 11, d = ch & (DIN - 1);
  const float dtw = dt_w[d], dtb = dt_b[d], Dd = Dp[d];
  float4 al = *reinterpret_cast<const float4*>(&A_log[d * 16 + q * 4]);
  const float An0 = -__expf(al.x), An1 = -__expf(al.y),
              An2 = -__expf(al.z), An3 = -__expf(al.w);
  float4 h4 = *reinterpret_cast<const float4*>(&hinit[((size_t)g * 8192 + ch) * 16 + q * 4]);
  float h0 = h4.x, h1 = h4.y, h2 = h4.z, h3 = h4.w;
  int row = b * SEQLEN + g * CHUNK;
  float dl = xd[(size_t)row * 128];
  float xv = x_cy[(size_t)row * DIN + d];
  float4 B4 = *reinterpret_cast<const float4*>(&xd[(size_t)row * 128 + 4 + q * 4]);
  float4 C4 = *reinterpret_cast<const float4*>(&xd[(size_t)row * 128 + 20 + q * 4]);
  for (int l = 0; l < CHUNK; l++, row++) {
    int rn = row + (l < CHUNK - 1 ? 1 : 0);
    float dl_n = xd[(size_t)rn * 128];
    float xv_n = x_cy[(size_t)rn * DIN + d];
    float4 B4n = *reinterpret_cast<const float4*>(&xd[(size_t)rn * 128 + 4 + q * 4]);
    float4 C4n = *reinterpret_cast<const float4*>(&xd[(size_t)rn * 128 + 20 + q * 4]);
    float z = fmaf(dl, dtw, dtb);
    float delta = __logf(1.f + __expf(z));
    float dx = delta * xv;
    h0 = fmaf(__expf(delta * An0), h0, B4.x * dx);
    h1 = fmaf(__expf(delta * An1), h1, B4.y * dx);
    h2 = fmaf(__expf(delta * An2), h2, B4.z * dx);
    h3 = fmaf(__expf(delta * An3), h3, B4.w * dx);
    float y = fmaf(h0, C4.x, fmaf(h1, C4.y, fmaf(h2, C4.z, h3 * C4.w)));
    y += __shfl_xor(y, 16);
    y += __shfl_xor(y, 32);
    if (q == 0) x_cy[(size_t)row * DIN + d] = fmaf(Dd, xv, y);
    dl = dl_n; xv = xv_n; B4 = B4n; C4 = C4n;
  }
}

// ---------------------------------------------------------------------------
extern "C" void kernel_launch(void* const* d_in, const int* in_sizes, int n_in,
                              void* d_out, int out_size, void* d_ws, size_t ws_size,
                              hipStream_t stream) {
  const float* x         = (const float*)d_in[0];  // (4,2048,1024)
  const float* in_proj_w = (const float*)d_in[1];  // (1024,4096)
  const float* conv_w    = (const float*)d_in[2];  // (2048,1,4)
  const float* conv_b    = (const float*)d_in[3];  // (2048,)
  const float* x_proj_w  = (const float*)d_in[4];  // (2048,33)
  const float* dt_proj_w = (const float*)d_in[5];  // (1,2048)
  const float* dt_proj_b = (const float*)d_in[6];  // (2048,)
  const float* A_log     = (const float*)d_in[7];  // (2048,16)
  const float* Dp        = (const float*)d_in[8];  // (2048,)
  const float* out_proj_w= (const float*)d_in[9];  // (2048,1024)
  float* out = (float*)d_out;                      // (4,2048,1024)

  // Workspace (within the proven 202,407,936 B footprint):
  //  R0 [0,64MiB) — time-multiplexed:
  //    phase1 (steps 0-2): xssm f32 [0,64M)
  //    phase2 (post-conv): x_cb bf16 [0,32M) | xdbl128 f32 [32M,36M) |
  //                        sumdl [36M,36.5M) | hend 8M [36.5M,44.5M) |
  //                        hinit 8M [44.5M,52.5M) | wt3 4M [52.5M,56.5M) |
  //                        wtp 0.5M [56.5M,57M)
  //    phase3 (step 5+):   gated bf16 [0,32M) (x_cb dead after xdbl gemm)
  //  R1 [64MiB,128MiB): gate f32 = silu(res) (live gemm1 -> step 5)
  //  R2 [128MiB,192MiB): xb bf16 16M + wt1 8M (dead after gemm1) -> x_c f32 64M
  char* ws = (char*)d_ws;
  float*          xssm   = (float*)ws;
  __hip_bfloat16* x_cb   = (__hip_bfloat16*)ws;                    // 32 MB
  float*          xdbl128= (float*)(ws + 33554432);                // 4 MB
  float*          sumdl  = (float*)(ws + 37748736);                // 512 KB
  float*          hend   = (float*)(ws + 38273024);                // 8 MB
  float*          hinit  = (float*)(ws + 46661632);                // 8 MB
  __hip_bfloat16* wt3    = (__hip_bfloat16*)(ws + 55050240);       // 4 MB
  __hip_bfloat16* wtp    = (__hip_bfloat16*)(ws + 59244544);       // 512 KB
  __hip_bfloat16* gated  = (__hip_bfloat16*)ws;                    // 32 MB (phase3)
  float*          gate   = (float*)(ws + 67108864);                // R1
  char* regB = ws + 134217728;                                     // R2
  __hip_bfloat16* xb     = (__hip_bfloat16*)regB;
  __hip_bfloat16* wt1    = (__hip_bfloat16*)(regB + (size_t)NROWS * 1024 * 2);
  float*          x_c    = (float*)regB;

  // 0) prologue: x -> bf16; in_proj_w -> bf16 transposed [4096][1024]
  convert_bf16<<<(NROWS * 1024) / 1024, 256, 0, stream>>>(x, xb, NROWS * 1024);
  transpose_bf16<<<dim3(4096 / 32, 1024 / 32), dim3(32, 8), 0, stream>>>(in_proj_w, wt1, 1024, 4096);

  // 1) gemm1: [xssm | silu(res)->gate] = x @ in_proj_w (8192x4096, K=1024)
  gemm_bf16<<<dim3(4096 / 128, NROWS / 128), 256, 0, stream>>>(xb, wt1, xssm, gate, NROWS, 4096, 1024);

  // 2) depthwise conv + silu -> x_c (overwrites xb/wt1, dead)
  conv_silu_kernel<<<(NROWS * DIN) / 256, 256, 0, stream>>>(xssm, conv_w, conv_b, x_c);

  // 3) x_proj as MFMA GEMM: x_cb = bf16(x_c); wtp = packed x_proj_w^T;
  //    xdbl128[8192][128] = x_cb @ wtp^T   (xssm dead -> R0 phase2)
  convert_bf16<<<(NROWS * DIN) / 1024, 256, 0, stream>>>(x_c, x_cb, NROWS * DIN);
  pack_xproj<<<(128 * 2048) / 256, 256, 0, stream>>>(x_proj_w, wtp);
  gemm_bf16<<<dim3(1, NROWS / 128), 256, 0, stream>>>(x_cb, wtp, xdbl128, (float*)nullptr, NROWS, 128, 2048);

  // 4) chunked selective scan (3 passes), in-place on x_c (stores y + D*x)
  scan_passA<<<dim3(512, GCH / 4), 256, 0, stream>>>(x_c, xdbl128, dt_proj_w, dt_proj_b, A_log, hend, sumdl);
  scan_passB<<<128, 256, 0, stream>>>(A_log, sumdl, hend, hinit);
  scan_passC<<<dim3(512, GCH / 4), 256, 0, stream>>>(x_c, xdbl128, dt_proj_w, dt_proj_b, A_log, Dp, hinit);

  // 5) gated bf16 = bf16(x_c * gate) into R0 (x_cb/scan scratch dead)
  gate_convert_bf16<<<(NROWS * DIN) / 1024, 256, 0, stream>>>(x_c, gate, gated, NROWS * DIN);

  // 6) out_proj_w -> bf16 transposed [1024][2048]
  transpose_bf16<<<dim3(1024 / 32, 2048 / 32), dim3(32, 8), 0, stream>>>(out_proj_w, wt3, 2048, 1024);

  // 7) out = gated @ out_proj_w (8192x1024, K=2048)
  gemm_bf16<<<dim3(1024 / 128, NROWS / 128), 256, 0, stream>>>(gated, wt3, out, (float*)nullptr, NROWS, 1024, 2048);
}

// Round 7
// 619.027 us; speedup vs baseline: 3.7176x; 1.0329x over previous
//
#include <hip/hip_runtime.h>
#include <hip/hip_bf16.h>
#include <math.h>

// MambaBlock: N_EMBD=1024, EXPAND=2 -> D_INNER=2048, D_STATE=16, D_CONV=4,
// DT_RANK=1, B=4, L=2048.
#define SEQLEN 2048
#define NROWS  8192            // B * L
#define DIN    2048            // d_inner
#define CHUNK  128             // scan chunk length
#define GCH    16              // SEQLEN / CHUNK

typedef __attribute__((ext_vector_type(8))) short short8;   // 8 bf16 (4 VGPRs)
typedef __attribute__((ext_vector_type(4))) float floatx4;  // MFMA accumulator

__device__ __forceinline__ float silu_f(float z) { return z / (1.f + __expf(-z)); }

// async global->LDS, 16 B per lane (wave-uniform base + lane*16).
__device__ __forceinline__ void gld_lds16(const void* gptr, void* lptr) {
  __builtin_amdgcn_global_load_lds((__attribute__((address_space(1))) unsigned int*)gptr,
                                   (__attribute__((address_space(3))) unsigned int*)lptr,
                                   16, 0, 0);
}

// ---------------------------------------------------------------------------
// bf16 MFMA GEMM (m97 structure + XOR bank swizzle): C = A[M][K] x Bt[N][K]^T.
// 128x128 tile, BK=64, 256 threads = 4 waves (2x2), each wave 64x64.
// LDS layout: tile[r][j] (j = 16B k-block 0..7) holds global k-block j^(r&7).
// Reader uses column J^(l15&7); each 8-lane phase then tiles all 32 banks
// exactly once -> conflict-free (was ~8-way, 2.5e7 conflict cycles/launch).
// If Cgate != nullptr: output split at N/2 — cols [0,N/2) -> C (ld N/2),
// cols [N/2,N) -> silu(acc) into Cgate (ld N/2). Else plain C with ld N.
// ---------------------------------------------------------------------------
__global__ __launch_bounds__(256) void gemm_bf16(const __hip_bfloat16* __restrict__ A,
                                                 const __hip_bfloat16* __restrict__ Bt,
                                                 float* __restrict__ C,
                                                 float* __restrict__ Cgate,
                                                 int M, int N, int K) {
  __shared__ unsigned short As[128 * 64];  // [r][k-swizzled], 16 KB
  __shared__ unsigned short Bs[128 * 64];  // [n][k-swizzled], 16 KB
  const int tid  = threadIdx.x;
  const int lane = tid & 63;
  const int quad = lane >> 4;
  const int l15  = lane & 15;
  const int wv   = tid >> 6;
  const int wm   = wv >> 1;
  const int wn   = wv & 1;
  const int row0 = blockIdx.y * 128;
  const int col0 = blockIdx.x * 128;
  const int swz  = l15 & 7;      // reader swizzle key (row & 7)

  floatx4 acc[4][4] = {};

  for (int k0 = 0; k0 < K; k0 += 64) {
    // Stage 128 rows x 64 bf16 per matrix. Chunk c = tid + i*256:
    // row r = c>>3, LDS col j = c&7 holds global k-block j^(r&7).
#pragma unroll
    for (int i = 0; i < 4; i++) {
      int c = tid + i * 256;
      int r = c >> 3, j = c & 7;
      int js = j ^ (r & 7);
      gld_lds16(A + (size_t)(row0 + r) * K + k0 + js * 8,
                (char*)As + (size_t)(i * 256 + wv * 64) * 16);
      gld_lds16(Bt + (size_t)(col0 + r) * K + k0 + js * 8,
                (char*)Bs + (size_t)(i * 256 + wv * 64) * 16);
    }
    __syncthreads();
#pragma unroll
    for (int ks = 0; ks < 64; ks += 32) {
      const int sj = (((ks >> 3) + quad) ^ swz) << 3;  // swizzled k-offset
      short8 a[4], b[4];
#pragma unroll
      for (int t = 0; t < 4; t++) {
        a[t] = *(const short8*)&As[(wm * 64 + t * 16 + l15) * 64 + sj];
        b[t] = *(const short8*)&Bs[(wn * 64 + t * 16 + l15) * 64 + sj];
      }
#pragma unroll
      for (int tm = 0; tm < 4; tm++)
#pragma unroll
        for (int tn = 0; tn < 4; tn++)
          acc[tm][tn] = __builtin_amdgcn_mfma_f32_16x16x32_bf16(a[tm], b[tn], acc[tm][tn], 0, 0, 0);
    }
    __syncthreads();
  }
  // C/D layout: col = lane&15, row = quad*4 + reg.
  const int Nh = N >> 1;
#pragma unroll
  for (int tm = 0; tm < 4; tm++) {
    int rbase = row0 + wm * 64 + tm * 16 + quad * 4;
#pragma unroll
    for (int tn = 0; tn < 4; tn++) {
      int col = col0 + wn * 64 + tn * 16 + l15;
#pragma unroll
      for (int r = 0; r < 4; r++) {
        float v = acc[tm][tn][r];
        if (Cgate) {
          if (col < Nh) C[(size_t)(rbase + r) * Nh + col] = v;
          else          Cgate[(size_t)(rbase + r) * Nh + col - Nh] = silu_f(v);
        } else {
          C[(size_t)(rbase + r) * N + col] = v;
        }
      }
    }
  }
}

// ---------------------------------------------------------------------------
// fp32 -> bf16 convert (n % 1024 == 0).
// ---------------------------------------------------------------------------
__global__ __launch_bounds__(256) void convert_bf16(const float* __restrict__ in,
                                                    __hip_bfloat16* __restrict__ out,
                                                    int n) {
  int i = (blockIdx.x * 256 + threadIdx.x) * 4;
  if (i >= n) return;
  float4 v = *reinterpret_cast<const float4*>(in + i);
  out[i + 0] = __float2bfloat16(v.x);
  out[i + 1] = __float2bfloat16(v.y);
  out[i + 2] = __float2bfloat16(v.z);
  out[i + 3] = __float2bfloat16(v.w);
}

// ---------------------------------------------------------------------------
// gated convert: out_bf16[i] = bf16(yraw[i] * gate[i])   (gate = silu(res))
// ---------------------------------------------------------------------------
__global__ __launch_bounds__(256) void gate_convert_bf16(const float* __restrict__ yraw,
                                                         const float* __restrict__ gate,
                                                         __hip_bfloat16* __restrict__ out,
                                                         int n) {
  int i = (blockIdx.x * 256 + threadIdx.x) * 4;
  if (i >= n) return;
  float4 y = *reinterpret_cast<const float4*>(yraw + i);
  float4 g = *reinterpret_cast<const float4*>(gate + i);
  out[i + 0] = __float2bfloat16(y.x * g.x);
  out[i + 1] = __float2bfloat16(y.y * g.y);
  out[i + 2] = __float2bfloat16(y.z * g.z);
  out[i + 3] = __float2bfloat16(y.w * g.w);
}

// ---------------------------------------------------------------------------
// Transpose + convert: w[K][N] f32 -> wt[N][K] bf16. 32x32 LDS tiles.
// ---------------------------------------------------------------------------
__global__ __launch_bounds__(256) void transpose_bf16(const float* __restrict__ w,
                                                      __hip_bfloat16* __restrict__ wt,
                                                      int K, int N) {
  __shared__ float tile[32][33];
  int n0 = blockIdx.x * 32, k0 = blockIdx.y * 32;
  int tx = threadIdx.x;
#pragma unroll
  for (int i = threadIdx.y; i < 32; i += 8)
    tile[i][tx] = w[(size_t)(k0 + i) * N + n0 + tx];
  __syncthreads();
#pragma unroll
  for (int i = threadIdx.y; i < 32; i += 8)
    wt[(size_t)(n0 + i) * K + k0 + tx] = __float2bfloat16(tile[tx][i]);
}

// ---------------------------------------------------------------------------
// Pack x_proj_w[2048][33] f32 -> wtp[128][2048] bf16 (transposed + padded):
//   row 0 <- delta col; rows 4..19 <- B cols 1..16; rows 20..35 <- C cols
//   17..32 (src = n-3); other rows zero. Keeps scan float4 reads 16B-aligned.
// ---------------------------------------------------------------------------
__global__ __launch_bounds__(256) void pack_xproj(const float* __restrict__ w,
                                                  __hip_bfloat16* __restrict__ wtp) {
  int idx = blockIdx.x * 256 + threadIdx.x;   // 0 .. 128*2048-1
  int n = idx >> 11;          // padded row 0..127
  int k = idx & 2047;         // 0..2047
  int src = (n == 0) ? 0 : ((n >= 4 && n < 36) ? (n - 3) : -1);
  float v = (src >= 0) ? w[(size_t)k * 33 + src] : 0.f;
  wtp[idx] = __float2bfloat16(v);
}

// ---------------------------------------------------------------------------
// Depthwise causal conv (width 4) + SiLU. xssm [NROWS][2048] -> x_c [NROWS][2048].
// ---------------------------------------------------------------------------
__global__ __launch_bounds__(256) void conv_silu_kernel(const float* __restrict__ xssm,
                                                        const float* __restrict__ conv_w,
                                                        const float* __restrict__ conv_b,
                                                        float* __restrict__ x_c) {
  int idx = blockIdx.x * blockDim.x + threadIdx.x;
  if (idx >= NROWS * DIN) return;
  int d = idx & (DIN - 1);
  int row = idx >> 11;
  int l = row & (SEQLEN - 1);
  float acc = conv_b[d];
#pragma unroll
  for (int k = 0; k < 4; k++) {
    int ls = l + k - 3;
    if (ls >= 0) acc = fmaf(conv_w[d * 4 + k], xssm[(size_t)(row + k - 3) * DIN + d], acc);
  }
  x_c[idx] = silu_f(acc);
}

// ---------------------------------------------------------------------------
// Chunked selective scan, 3 passes. delta/B/C come from xd = xdbl128[row][128]:
//   dl = xd[row*128], B4 = xd[row*128+4+q*4], C4 = xd[row*128+20+q*4].
// Mapping (passes A/C): 256-thr block = 4 waves; wave w handles chunk
// g = blockIdx.y*4+w for 16 channels; lane = q*16+c. grid (512, 4).
// ---------------------------------------------------------------------------
__global__ __launch_bounds__(256) void scan_passA(const float* __restrict__ x_c,
                                                  const float* __restrict__ xd,
                                                  const float* __restrict__ dt_w,
                                                  const float* __restrict__ dt_b,
                                                  const float* __restrict__ A_log,
                                                  float* __restrict__ hend,
                                                  float* __restrict__ sumdelta) {
  const int tid = threadIdx.x;
  const int lane = tid & 63;
  const int q = lane >> 4, c = lane & 15;
  const int g = blockIdx.y * 4 + (tid >> 6);
  const int ch = blockIdx.x * 16 + c;
  const int b = ch >> 11, d = ch & (DIN - 1);
  const float dtw = dt_w[d], dtb = dt_b[d];
  float4 al = *reinterpret_cast<const float4*>(&A_log[d * 16 + q * 4]);
  const float An0 = -__expf(al.x), An1 = -__expf(al.y),
              An2 = -__expf(al.z), An3 = -__expf(al.w);
  float h0 = 0.f, h1 = 0.f, h2 = 0.f, h3 = 0.f, sd = 0.f;
  int row = b * SEQLEN + g * CHUNK;
  float dl = xd[(size_t)row * 128];
  float xv = x_c[(size_t)row * DIN + d];
  float4 B4 = *reinterpret_cast<const float4*>(&xd[(size_t)row * 128 + 4 + q * 4]);
  for (int l = 0; l < CHUNK; l++, row++) {
    int rn = row + (l < CHUNK - 1 ? 1 : 0);
    float dl_n = xd[(size_t)rn * 128];
    float xv_n = x_c[(size_t)rn * DIN + d];
    float4 B4n = *reinterpret_cast<const float4*>(&xd[(size_t)rn * 128 + 4 + q * 4]);
    float z = fmaf(dl, dtw, dtb);
    float delta = __logf(1.f + __expf(z));
    sd += delta;
    float dx = delta * xv;
    h0 = fmaf(__expf(delta * An0), h0, B4.x * dx);
    h1 = fmaf(__expf(delta * An1), h1, B4.y * dx);
    h2 = fmaf(__expf(delta * An2), h2, B4.z * dx);
    h3 = fmaf(__expf(delta * An3), h3, B4.w * dx);
    dl = dl_n; xv = xv_n; B4 = B4n;
  }
  // hend layout [g][ch][16] for coalescing.
  size_t base = ((size_t)g * 8192 + ch) * 16 + q * 4;
  float4 hv = {h0, h1, h2, h3};
  *reinterpret_cast<float4*>(&hend[base]) = hv;
  if (q == 0) sumdelta[g * 8192 + ch] = sd;
}

// Combine chunk summaries: hinit[g] = exp(A*sumdelta[g-1])*hinit[g-1] + hend[g-1].
__global__ __launch_bounds__(256) void scan_passB(const float* __restrict__ A_log,
                                                  const float* __restrict__ sumdelta,
                                                  const float* __restrict__ hend,
                                                  float* __restrict__ hinit) {
  int t = blockIdx.x * 256 + threadIdx.x;   // 0..32767
  int ch = t >> 2, q = t & 3;
  int d = ch & (DIN - 1);
  float4 al = *reinterpret_cast<const float4*>(&A_log[d * 16 + q * 4]);
  const float An0 = -__expf(al.x), An1 = -__expf(al.y),
              An2 = -__expf(al.z), An3 = -__expf(al.w);
  float4 h = {0.f, 0.f, 0.f, 0.f};
#pragma unroll
  for (int g = 0; g < GCH; g++) {
    size_t base = ((size_t)g * 8192 + ch) * 16 + q * 4;
    *reinterpret_cast<float4*>(&hinit[base]) = h;
    float sd = sumdelta[g * 8192 + ch];
    float4 he = *reinterpret_cast<const float4*>(&hend[base]);
    h.x = fmaf(__expf(An0 * sd), h.x, he.x);
    h.y = fmaf(__expf(An1 * sd), h.y, he.y);
    h.z = fmaf(__expf(An2 * sd), h.z, he.z);
    h.w = fmaf(__expf(An3 * sd), h.w, he.w);
  }
}

__global__ __launch_bounds__(256) void scan_passC(float* __restrict__ x_cy,
                                                  const float* __restrict__ xd,
                                                  const float* __restrict__ dt_w,
                                                  const float* __restrict__ dt_b,
                                                  const float* __restrict__ A_log,
                                                  const float* __restrict__ Dp,
                                                  const float* __restrict__ hinit) {
  const int tid = threadIdx.x;
  const int lane = tid & 63;
  const int q = lane >> 4, c = lane & 15;
  const int g = blockIdx.y * 4 + (tid >> 6);
  const int ch = blockIdx.x * 16 + c;
  const int b = ch >> 11, d = ch & (DIN - 1);
  const float dtw = dt_w[d], dtb = dt_b[d], Dd = Dp[d];
  float4 al = *reinterpret_cast<const float4*>(&A_log[d * 16 + q * 4]);
  const float An0 = -__expf(al.x), An1 = -__expf(al.y),
              An2 = -__expf(al.z), An3 = -__expf(al.w);
  float4 h4 = *reinterpret_cast<const float4*>(&hinit[((size_t)g * 8192 + ch) * 16 + q * 4]);
  float h0 = h4.x, h1 = h4.y, h2 = h4.z, h3 = h4.w;
  int row = b * SEQLEN + g * CHUNK;
  float dl = xd[(size_t)row * 128];
  float xv = x_cy[(size_t)row * DIN + d];
  float4 B4 = *reinterpret_cast<const float4*>(&xd[(size_t)row * 128 + 4 + q * 4]);
  float4 C4 = *reinterpret_cast<const float4*>(&xd[(size_t)row * 128 + 20 + q * 4]);
  for (int l = 0; l < CHUNK; l++, row++) {
    int rn = row + (l < CHUNK - 1 ? 1 : 0);
    float dl_n = xd[(size_t)rn * 128];
    float xv_n = x_cy[(size_t)rn * DIN + d];
    float4 B4n = *reinterpret_cast<const float4*>(&xd[(size_t)rn * 128 + 4 + q * 4]);
    float4 C4n = *reinterpret_cast<const float4*>(&xd[(size_t)rn * 128 + 20 + q * 4]);
    float z = fmaf(dl, dtw, dtb);
    float delta = __logf(1.f + __expf(z));
    float dx = delta * xv;
    h0 = fmaf(__expf(delta * An0), h0, B4.x * dx);
    h1 = fmaf(__expf(delta * An1), h1, B4.y * dx);
    h2 = fmaf(__expf(delta * An2), h2, B4.z * dx);
    h3 = fmaf(__expf(delta * An3), h3, B4.w * dx);
    float y = fmaf(h0, C4.x, fmaf(h1, C4.y, fmaf(h2, C4.z, h3 * C4.w)));
    y += __shfl_xor(y, 16);
    y += __shfl_xor(y, 32);
    if (q == 0) x_cy[(size_t)row * DIN + d] = fmaf(Dd, xv, y);
    dl = dl_n; xv = xv_n; B4 = B4n; C4 = C4n;
  }
}

// ---------------------------------------------------------------------------
extern "C" void kernel_launch(void* const* d_in, const int* in_sizes, int n_in,
                              void* d_out, int out_size, void* d_ws, size_t ws_size,
                              hipStream_t stream) {
  const float* x         = (const float*)d_in[0];  // (4,2048,1024)
  const float* in_proj_w = (const float*)d_in[1];  // (1024,4096)
  const float* conv_w    = (const float*)d_in[2];  // (2048,1,4)
  const float* conv_b    = (const float*)d_in[3];  // (2048,)
  const float* x_proj_w  = (const float*)d_in[4];  // (2048,33)
  const float* dt_proj_w = (const float*)d_in[5];  // (1,2048)
  const float* dt_proj_b = (const float*)d_in[6];  // (2048,)
  const float* A_log     = (const float*)d_in[7];  // (2048,16)
  const float* Dp        = (const float*)d_in[8];  // (2048,)
  const float* out_proj_w= (const float*)d_in[9];  // (2048,1024)
  float* out = (float*)d_out;                      // (4,2048,1024)

  // Workspace (within the proven 202,407,936 B footprint):
  //  R0 [0,64MiB) — time-multiplexed:
  //    phase1 (steps 0-2): xssm f32 [0,64M)
  //    phase2 (post-conv): x_cb bf16 [0,32M) | xdbl128 f32 [32M,36M) |
  //                        sumdl [36M,36.5M) | hend 8M | hinit 8M |
  //                        wt3 4M | wtp 0.5M
  //    phase3 (step 5+):   gated bf16 [0,32M)
  //  R1 [64MiB,128MiB): gate f32 = silu(res) (live gemm1 -> step 5)
  //  R2 [128MiB,192MiB): xb bf16 16M + wt1 8M (dead after gemm1) -> x_c f32 64M
  char* ws = (char*)d_ws;
  float*          xssm   = (float*)ws;
  __hip_bfloat16* x_cb   = (__hip_bfloat16*)ws;                    // 32 MB
  float*          xdbl128= (float*)(ws + 33554432);                // 4 MB
  float*          sumdl  = (float*)(ws + 37748736);                // 512 KB
  float*          hend   = (float*)(ws + 38273024);                // 8 MB
  float*          hinit  = (float*)(ws + 46661632);                // 8 MB
  __hip_bfloat16* wt3    = (__hip_bfloat16*)(ws + 55050240);       // 4 MB
  __hip_bfloat16* wtp    = (__hip_bfloat16*)(ws + 59244544);       // 512 KB
  __hip_bfloat16* gated  = (__hip_bfloat16*)ws;                    // 32 MB (phase3)
  float*          gate   = (float*)(ws + 67108864);                // R1
  char* regB = ws + 134217728;                                     // R2
  __hip_bfloat16* xb     = (__hip_bfloat16*)regB;
  __hip_bfloat16* wt1    = (__hip_bfloat16*)(regB + (size_t)NROWS * 1024 * 2);
  float*          x_c    = (float*)regB;

  // 0) prologue: x -> bf16; in_proj_w -> bf16 transposed [4096][1024]
  convert_bf16<<<(NROWS * 1024) / 1024, 256, 0, stream>>>(x, xb, NROWS * 1024);
  transpose_bf16<<<dim3(4096 / 32, 1024 / 32), dim3(32, 8), 0, stream>>>(in_proj_w, wt1, 1024, 4096);

  // 1) gemm1: [xssm | silu(res)->gate] = x @ in_proj_w (8192x4096, K=1024)
  gemm_bf16<<<dim3(4096 / 128, NROWS / 128), 256, 0, stream>>>(xb, wt1, xssm, gate, NROWS, 4096, 1024);

  // 2) depthwise conv + silu -> x_c (overwrites xb/wt1, dead)
  conv_silu_kernel<<<(NROWS * DIN) / 256, 256, 0, stream>>>(xssm, conv_w, conv_b, x_c);

  // 3) x_proj as MFMA GEMM: x_cb = bf16(x_c); wtp = packed x_proj_w^T;
  //    xdbl128[8192][128] = x_cb @ wtp^T   (xssm dead -> R0 phase2)
  convert_bf16<<<(NROWS * DIN) / 1024, 256, 0, stream>>>(x_c, x_cb, NROWS * DIN);
  pack_xproj<<<(128 * 2048) / 256, 256, 0, stream>>>(x_proj_w, wtp);
  gemm_bf16<<<dim3(1, NROWS / 128), 256, 0, stream>>>(x_cb, wtp, xdbl128, (float*)nullptr, NROWS, 128, 2048);

  // 4) chunked selective scan (3 passes), in-place on x_c (stores y + D*x)
  scan_passA<<<dim3(512, GCH / 4), 256, 0, stream>>>(x_c, xdbl128, dt_proj_w, dt_proj_b, A_log, hend, sumdl);
  scan_passB<<<128, 256, 0, stream>>>(A_log, sumdl, hend, hinit);
  scan_passC<<<dim3(512, GCH / 4), 256, 0, stream>>>(x_c, xdbl128, dt_proj_w, dt_proj_b, A_log, Dp, hinit);

  // 5) gated bf16 = bf16(x_c * gate) into R0 (x_cb/scan scratch dead)
  gate_convert_bf16<<<(NROWS * DIN) / 1024, 256, 0, stream>>>(x_c, gate, gated, NROWS * DIN);

  // 6) out_proj_w -> bf16 transposed [1024][2048]
  transpose_bf16<<<dim3(1024 / 32, 2048 / 32), dim3(32, 8), 0, stream>>>(out_proj_w, wt3, 2048, 1024);

  // 7) out = gated @ out_proj_w (8192x1024, K=2048)
  gemm_bf16<<<dim3(1024 / 128, NROWS / 128), 256, 0, stream>>>(gated, wt3, out, (float*)nullptr, NROWS, 1024, 2048);
}

// Round 9
// 614.472 us; speedup vs baseline: 3.7452x; 1.0074x over previous
//
#include <hip/hip_runtime.h>
#include <hip/hip_bf16.h>
#include <math.h>

// MambaBlock: N_EMBD=1024, EXPAND=2 -> D_INNER=2048, D_STATE=16, D_CONV=4,
// DT_RANK=1, B=4, L=2048.
#define SEQLEN 2048
#define NROWS  8192            // B * L
#define DIN    2048            // d_inner
#define CHUNK  128             // scan chunk length
#define GCH    16              // SEQLEN / CHUNK

typedef __attribute__((ext_vector_type(8))) short short8;   // 8 bf16 (4 VGPRs)
typedef __attribute__((ext_vector_type(4))) float floatx4;  // MFMA accumulator

__device__ __forceinline__ float silu_f(float z) { return z / (1.f + __expf(-z)); }
__device__ __forceinline__ float bfbits2f(unsigned short u) {
  return __uint_as_float(((unsigned int)u) << 16);
}

// async global->LDS, 16 B per lane (wave-uniform base + lane*16).
__device__ __forceinline__ void gld_lds16(const void* gptr, void* lptr) {
  __builtin_amdgcn_global_load_lds((__attribute__((address_space(1))) unsigned int*)gptr,
                                   (__attribute__((address_space(3))) unsigned int*)lptr,
                                   16, 0, 0);
}

// ---------------------------------------------------------------------------
// bf16 MFMA GEMM (m97 structure + XOR bank swizzle): C = A[M][K] x Bt[N][K]^T.
// 128x128 tile, BK=64, 256 threads = 4 waves (2x2), each wave 64x64.
// LDS: tile[r][j] (j = 16B k-block) holds global k-block j^(r&7); reader uses
// J^(l15&7) -> conflict-free (verified: SQ_LDS_BANK_CONFLICT 2.5e7 -> 0).
// Epilogue modes:
//   Cb != nullptr: split bf16 — cols [0,N/2) -> Cb, cols [N/2,N) -> silu -> Gb
//                  (both ld N/2).  [gemm1: xssm_bf | gate_bf]
//   else:          plain fp32 C, ld N.  [xdbl gemm, gemm3]
// ---------------------------------------------------------------------------
__global__ __launch_bounds__(256) void gemm_bf16(const __hip_bfloat16* __restrict__ A,
                                                 const __hip_bfloat16* __restrict__ Bt,
                                                 float* __restrict__ C,
                                                 __hip_bfloat16* __restrict__ Cb,
                                                 __hip_bfloat16* __restrict__ Gb,
                                                 int M, int N, int K) {
  __shared__ unsigned short As[128 * 64];  // [r][k-swizzled], 16 KB
  __shared__ unsigned short Bs[128 * 64];  // [n][k-swizzled], 16 KB
  const int tid  = threadIdx.x;
  const int lane = tid & 63;
  const int quad = lane >> 4;
  const int l15  = lane & 15;
  const int wv   = tid >> 6;
  const int wm   = wv >> 1;
  const int wn   = wv & 1;
  const int row0 = blockIdx.y * 128;
  const int col0 = blockIdx.x * 128;
  const int swz  = l15 & 7;      // reader swizzle key (row & 7)

  floatx4 acc[4][4] = {};

  for (int k0 = 0; k0 < K; k0 += 64) {
#pragma unroll
    for (int i = 0; i < 4; i++) {
      int c = tid + i * 256;
      int r = c >> 3, j = c & 7;
      int js = j ^ (r & 7);
      gld_lds16(A + (size_t)(row0 + r) * K + k0 + js * 8,
                (char*)As + (size_t)(i * 256 + wv * 64) * 16);
      gld_lds16(Bt + (size_t)(col0 + r) * K + k0 + js * 8,
                (char*)Bs + (size_t)(i * 256 + wv * 64) * 16);
    }
    __syncthreads();
#pragma unroll
    for (int ks = 0; ks < 64; ks += 32) {
      const int sj = (((ks >> 3) + quad) ^ swz) << 3;  // swizzled k-offset
      short8 a[4], b[4];
#pragma unroll
      for (int t = 0; t < 4; t++) {
        a[t] = *(const short8*)&As[(wm * 64 + t * 16 + l15) * 64 + sj];
        b[t] = *(const short8*)&Bs[(wn * 64 + t * 16 + l15) * 64 + sj];
      }
#pragma unroll
      for (int tm = 0; tm < 4; tm++)
#pragma unroll
        for (int tn = 0; tn < 4; tn++)
          acc[tm][tn] = __builtin_amdgcn_mfma_f32_16x16x32_bf16(a[tm], b[tn], acc[tm][tn], 0, 0, 0);
    }
    __syncthreads();
  }
  // C/D layout: col = lane&15, row = quad*4 + reg.
  const int Nh = N >> 1;
#pragma unroll
  for (int tm = 0; tm < 4; tm++) {
    int rbase = row0 + wm * 64 + tm * 16 + quad * 4;
#pragma unroll
    for (int tn = 0; tn < 4; tn++) {
      int col = col0 + wn * 64 + tn * 16 + l15;
#pragma unroll
      for (int r = 0; r < 4; r++) {
        float v = acc[tm][tn][r];
        if (Cb) {
          if (col < Nh) Cb[(size_t)(rbase + r) * Nh + col] = __float2bfloat16(v);
          else          Gb[(size_t)(rbase + r) * Nh + col - Nh] = __float2bfloat16(silu_f(v));
        } else {
          C[(size_t)(rbase + r) * N + col] = v;
        }
      }
    }
  }
}

// ---------------------------------------------------------------------------
// fp32 -> bf16 convert (n % 1024 == 0).
// ---------------------------------------------------------------------------
__global__ __launch_bounds__(256) void convert_bf16(const float* __restrict__ in,
                                                    __hip_bfloat16* __restrict__ out,
                                                    int n) {
  int i = (blockIdx.x * 256 + threadIdx.x) * 4;
  if (i >= n) return;
  float4 v = *reinterpret_cast<const float4*>(in + i);
  out[i + 0] = __float2bfloat16(v.x);
  out[i + 1] = __float2bfloat16(v.y);
  out[i + 2] = __float2bfloat16(v.z);
  out[i + 3] = __float2bfloat16(v.w);
}

// ---------------------------------------------------------------------------
// gated convert: out_bf16[i] = bf16(yraw[i] * gate[i]); gate stored as bf16.
// ---------------------------------------------------------------------------
__global__ __launch_bounds__(256) void gate_convert_bf16(const float* __restrict__ yraw,
                                                         const __hip_bfloat16* __restrict__ gate,
                                                         __hip_bfloat16* __restrict__ out,
                                                         int n) {
  int i = (blockIdx.x * 256 + threadIdx.x) * 4;
  if (i >= n) return;
  float4 y = *reinterpret_cast<const float4*>(yraw + i);
  ushort4 g = *reinterpret_cast<const ushort4*>(gate + i);
  out[i + 0] = __float2bfloat16(y.x * bfbits2f(g.x));
  out[i + 1] = __float2bfloat16(y.y * bfbits2f(g.y));
  out[i + 2] = __float2bfloat16(y.z * bfbits2f(g.z));
  out[i + 3] = __float2bfloat16(y.w * bfbits2f(g.w));
}

// ---------------------------------------------------------------------------
// Transpose + convert: w[K][N] f32 -> wt[N][K] bf16. 32x32 LDS tiles.
// ---------------------------------------------------------------------------
__global__ __launch_bounds__(256) void transpose_bf16(const float* __restrict__ w,
                                                      __hip_bfloat16* __restrict__ wt,
                                                      int K, int N) {
  __shared__ float tile[32][33];
  int n0 = blockIdx.x * 32, k0 = blockIdx.y * 32;
  int tx = threadIdx.x;
#pragma unroll
  for (int i = threadIdx.y; i < 32; i += 8)
    tile[i][tx] = w[(size_t)(k0 + i) * N + n0 + tx];
  __syncthreads();
#pragma unroll
  for (int i = threadIdx.y; i < 32; i += 8)
    wt[(size_t)(n0 + i) * K + k0 + tx] = __float2bfloat16(tile[tx][i]);
}

// ---------------------------------------------------------------------------
// Pack x_proj_w[2048][33] f32 -> wtp[128][2048] bf16 (transposed + padded):
//   row 0 <- delta col; rows 4..19 <- B cols 1..16; rows 20..35 <- C cols
//   17..32 (src = n-3); other rows zero. Keeps scan float4 reads 16B-aligned.
// ---------------------------------------------------------------------------
__global__ __launch_bounds__(256) void pack_xproj(const float* __restrict__ w,
                                                  __hip_bfloat16* __restrict__ wtp) {
  int idx = blockIdx.x * 256 + threadIdx.x;   // 0 .. 128*2048-1
  int n = idx >> 11;          // padded row 0..127
  int k = idx & 2047;         // 0..2047
  int src = (n == 0) ? 0 : ((n >= 4 && n < 36) ? (n - 3) : -1);
  float v = (src >= 0) ? w[(size_t)k * 33 + src] : 0.f;
  wtp[idx] = __float2bfloat16(v);
}

// ---------------------------------------------------------------------------
// Depthwise causal conv (width 4) + SiLU. bf16 in, fp32 out.
// xssm_bf [NROWS][2048] -> x_c [NROWS][2048] f32.
// ---------------------------------------------------------------------------
__global__ __launch_bounds__(256) void conv_silu_kernel(const __hip_bfloat16* __restrict__ xssm,
                                                        const float* __restrict__ conv_w,
                                                        const float* __restrict__ conv_b,
                                                        float* __restrict__ x_c) {
  int idx = blockIdx.x * blockDim.x + threadIdx.x;
  if (idx >= NROWS * DIN) return;
  int d = idx & (DIN - 1);
  int row = idx >> 11;
  int l = row & (SEQLEN - 1);
  float acc = conv_b[d];
#pragma unroll
  for (int k = 0; k < 4; k++) {
    int ls = l + k - 3;
    if (ls >= 0)
      acc = fmaf(conv_w[d * 4 + k],
                 __bfloat162float(xssm[(size_t)(row + k - 3) * DIN + d]), acc);
  }
  x_c[idx] = silu_f(acc);
}

// ---------------------------------------------------------------------------
// Chunked selective scan, 3 passes (PROVEN fp32 fabric from the 619us kernel).
// delta/B/C come from xd = xdbl128[row][128]:
//   dl = xd[row*128], B4 = xd[row*128+4+q*4], C4 = xd[row*128+20+q*4].
// Mapping (A/C): 256-thr block = 4 waves; wave w handles chunk g =
// blockIdx.y*4+w for 16 channels; lane = q*16+c. grid (512, 4).
// ---------------------------------------------------------------------------
__global__ __launch_bounds__(256) void scan_passA(const float* __restrict__ x_c,
                                                  const float* __restrict__ xd,
                                                  const float* __restrict__ dt_w,
                                                  const float* __restrict__ dt_b,
                                                  const float* __restrict__ A_log,
                                                  float* __restrict__ hend,
                                                  float* __restrict__ sumdelta) {
  const int tid = threadIdx.x;
  const int lane = tid & 63;
  const int q = lane >> 4, c = lane & 15;
  const int g = blockIdx.y * 4 + (tid >> 6);
  const int ch = blockIdx.x * 16 + c;
  const int b = ch >> 11, d = ch & (DIN - 1);
  const float dtw = dt_w[d], dtb = dt_b[d];
  float4 al = *reinterpret_cast<const float4*>(&A_log[d * 16 + q * 4]);
  const float An0 = -__expf(al.x), An1 = -__expf(al.y),
              An2 = -__expf(al.z), An3 = -__expf(al.w);
  float h0 = 0.f, h1 = 0.f, h2 = 0.f, h3 = 0.f, sd = 0.f;
  int row = b * SEQLEN + g * CHUNK;
  float dl = xd[(size_t)row * 128];
  float xv = x_c[(size_t)row * DIN + d];
  float4 B4 = *reinterpret_cast<const float4*>(&xd[(size_t)row * 128 + 4 + q * 4]);
  for (int l = 0; l < CHUNK; l++, row++) {
    int rn = row + (l < CHUNK - 1 ? 1 : 0);
    float dl_n = xd[(size_t)rn * 128];
    float xv_n = x_c[(size_t)rn * DIN + d];
    float4 B4n = *reinterpret_cast<const float4*>(&xd[(size_t)rn * 128 + 4 + q * 4]);
    float z = fmaf(dl, dtw, dtb);
    float delta = __logf(1.f + __expf(z));
    sd += delta;
    float dx = delta * xv;
    h0 = fmaf(__expf(delta * An0), h0, B4.x * dx);
    h1 = fmaf(__expf(delta * An1), h1, B4.y * dx);
    h2 = fmaf(__expf(delta * An2), h2, B4.z * dx);
    h3 = fmaf(__expf(delta * An3), h3, B4.w * dx);
    dl = dl_n; xv = xv_n; B4 = B4n;
  }
  // hend layout [g][ch][16] for coalescing.
  size_t base = ((size_t)g * 8192 + ch) * 16 + q * 4;
  float4 hv = {h0, h1, h2, h3};
  *reinterpret_cast<float4*>(&hend[base]) = hv;
  if (q == 0) sumdelta[g * 8192 + ch] = sd;
}

// Combine chunk summaries: hinit[g] = exp(A*sumdelta[g-1])*hinit[g-1] + hend[g-1].
__global__ __launch_bounds__(256) void scan_passB(const float* __restrict__ A_log,
                                                  const float* __restrict__ sumdelta,
                                                  const float* __restrict__ hend,
                                                  float* __restrict__ hinit) {
  int t = blockIdx.x * 256 + threadIdx.x;   // 0..32767
  int ch = t >> 2, q = t & 3;
  int d = ch & (DIN - 1);
  float4 al = *reinterpret_cast<const float4*>(&A_log[d * 16 + q * 4]);
  const float An0 = -__expf(al.x), An1 = -__expf(al.y),
              An2 = -__expf(al.z), An3 = -__expf(al.w);
  float4 h = {0.f, 0.f, 0.f, 0.f};
#pragma unroll
  for (int g = 0; g < GCH; g++) {
    size_t base = ((size_t)g * 8192 + ch) * 16 + q * 4;
    *reinterpret_cast<float4*>(&hinit[base]) = h;
    float sd = sumdelta[g * 8192 + ch];
    float4 he = *reinterpret_cast<const float4*>(&hend[base]);
    h.x = fmaf(__expf(An0 * sd), h.x, he.x);
    h.y = fmaf(__expf(An1 * sd), h.y, he.y);
    h.z = fmaf(__expf(An2 * sd), h.z, he.z);
    h.w = fmaf(__expf(An3 * sd), h.w, he.w);
  }
}

// Pass C: exact recurrence from hinit; writes y + D*x IN PLACE into x_c (fp32).
__global__ __launch_bounds__(256) void scan_passC(float* __restrict__ x_cy,
                                                  const float* __restrict__ xd,
                                                  const float* __restrict__ dt_w,
                                                  const float* __restrict__ dt_b,
                                                  const float* __restrict__ A_log,
                                                  const float* __restrict__ Dp,
                                                  const float* __restrict__ hinit) {
  const int tid = threadIdx.x;
  const int lane = tid & 63;
  const int q = lane >> 4, c = lane & 15;
  const int g = blockIdx.y * 4 + (tid >> 6);
  const int ch = blockIdx.x * 16 + c;
  const int b = ch >> 11, d = ch & (DIN - 1);
  const float dtw = dt_w[d], dtb = dt_b[d], Dd = Dp[d];
  float4 al = *reinterpret_cast<const float4*>(&A_log[d * 16 + q * 4]);
  const float An0 = -__expf(al.x), An1 = -__expf(al.y),
              An2 = -__expf(al.z), An3 = -__expf(al.w);
  float4 h4 = *reinterpret_cast<const float4*>(&hinit[((size_t)g * 8192 + ch) * 16 + q * 4]);
  float h0 = h4.x, h1 = h4.y, h2 = h4.z, h3 = h4.w;
  int row = b * SEQLEN + g * CHUNK;
  float dl = xd[(size_t)row * 128];
  float xv = x_cy[(size_t)row * DIN + d];
  float4 B4 = *reinterpret_cast<const float4*>(&xd[(size_t)row * 128 + 4 + q * 4]);
  float4 C4 = *reinterpret_cast<const float4*>(&xd[(size_t)row * 128 + 20 + q * 4]);
  for (int l = 0; l < CHUNK; l++, row++) {
    int rn = row + (l < CHUNK - 1 ? 1 : 0);
    float dl_n = xd[(size_t)rn * 128];
    float xv_n = x_cy[(size_t)rn * DIN + d];
    float4 B4n = *reinterpret_cast<const float4*>(&xd[(size_t)rn * 128 + 4 + q * 4]);
    float4 C4n = *reinterpret_cast<const float4*>(&xd[(size_t)rn * 128 + 20 + q * 4]);
    float z = fmaf(dl, dtw, dtb);
    float delta = __logf(1.f + __expf(z));
    float dx = delta * xv;
    h0 = fmaf(__expf(delta * An0), h0, B4.x * dx);
    h1 = fmaf(__expf(delta * An1), h1, B4.y * dx);
    h2 = fmaf(__expf(delta * An2), h2, B4.z * dx);
    h3 = fmaf(__expf(delta * An3), h3, B4.w * dx);
    float y = fmaf(h0, C4.x, fmaf(h1, C4.y, fmaf(h2, C4.z, h3 * C4.w)));
    y += __shfl_xor(y, 16);
    y += __shfl_xor(y, 32);
    if (q == 0) x_cy[(size_t)row * DIN + d] = fmaf(Dd, xv, y);
    dl = dl_n; xv = xv_n; B4 = B4n; C4 = C4n;
  }
}

// ---------------------------------------------------------------------------
extern "C" void kernel_launch(void* const* d_in, const int* in_sizes, int n_in,
                              void* d_out, int out_size, void* d_ws, size_t ws_size,
                              hipStream_t stream) {
  const float* x         = (const float*)d_in[0];  // (4,2048,1024)
  const float* in_proj_w = (const float*)d_in[1];  // (1024,4096)
  const float* conv_w    = (const float*)d_in[2];  // (2048,1,4)
  const float* conv_b    = (const float*)d_in[3];  // (2048,)
  const float* x_proj_w  = (const float*)d_in[4];  // (2048,33)
  const float* dt_proj_w = (const float*)d_in[5];  // (1,2048)
  const float* dt_proj_b = (const float*)d_in[6];  // (2048,)
  const float* A_log     = (const float*)d_in[7];  // (2048,16)
  const float* Dp        = (const float*)d_in[8];  // (2048,)
  const float* out_proj_w= (const float*)d_in[9];  // (2048,1024)
  float* out = (float*)d_out;                      // (4,2048,1024)

  // Workspace layout (max offset 192 MiB <= proven 202,407,936 B).
  // Time-multiplexed regions with disjoint live ranges:
  //  [0,16M):   xb bf16 (steps 0-1) -> xdbl128 4M | sumdl .5M | wtp .5M | wt3 4M
  //  [16,24M):  wt1 bf16 (steps 0-1) -> hend 8M (step 4+)
  //  [24,56M):  xssm_bf (steps 1-2)  -> x_cb bf16 (step 3)
  //  [56,88M):  gate_bf (live step 1 -> step 5)
  //  [88,152M): x_c fp32 (conv out; scan in-place; read step 5)
  //  [152,184M): gated bf16 (step 5 -> gemm3)
  //  [184,192M): hinit fp32
  const size_t MB = 1u << 20;
  char* ws = (char*)d_ws;
  __hip_bfloat16* xb      = (__hip_bfloat16*)(ws);                      // phase1
  float*          xdbl128 = (float*)(ws);                               // phase2, 4MB
  float*          sumdl   = (float*)(ws + 4 * MB);                      // 512KB
  __hip_bfloat16* wtp     = (__hip_bfloat16*)(ws + 4 * MB + 524288);    // 512KB
  __hip_bfloat16* wt3     = (__hip_bfloat16*)(ws + 5 * MB);             // 4MB
  __hip_bfloat16* wt1     = (__hip_bfloat16*)(ws + 16 * MB);            // phase1, 8MB
  float*          hend    = (float*)(ws + 16 * MB);                     // phase2, 8MB
  __hip_bfloat16* xssm_bf = (__hip_bfloat16*)(ws + 24 * MB);            // phase1, 32MB
  __hip_bfloat16* x_cb    = (__hip_bfloat16*)(ws + 24 * MB);            // phase2, 32MB
  __hip_bfloat16* gate_bf = (__hip_bfloat16*)(ws + 56 * MB);            // 32MB
  float*          x_c     = (float*)(ws + 88 * MB);                     // 64MB
  __hip_bfloat16* gated   = (__hip_bfloat16*)(ws + 152 * MB);           // 32MB
  float*          hinit   = (float*)(ws + 184 * MB);                    // 8MB

  // 0) prologue: x -> bf16; in_proj_w -> bf16 transposed [4096][1024]
  convert_bf16<<<(NROWS * 1024) / 1024, 256, 0, stream>>>(x, xb, NROWS * 1024);
  transpose_bf16<<<dim3(4096 / 32, 1024 / 32), dim3(32, 8), 0, stream>>>(in_proj_w, wt1, 1024, 4096);

  // 1) gemm1: [xssm_bf | silu(res)->gate_bf] = x @ in_proj_w (8192x4096, K=1024)
  gemm_bf16<<<dim3(4096 / 128, NROWS / 128), 256, 0, stream>>>(
      xb, wt1, (float*)nullptr, xssm_bf, gate_bf, NROWS, 4096, 1024);

  // 2) depthwise conv + silu: xssm_bf (bf16) -> x_c (fp32)
  conv_silu_kernel<<<(NROWS * DIN) / 256, 256, 0, stream>>>(xssm_bf, conv_w, conv_b, x_c);

  // 3) x_proj as MFMA GEMM: x_cb = bf16(x_c) (over dead xssm_bf);
  //    wtp = packed x_proj_w^T (over dead xb); xdbl128 = x_cb @ wtp^T
  convert_bf16<<<(NROWS * DIN) / 1024, 256, 0, stream>>>(x_c, x_cb, NROWS * DIN);
  pack_xproj<<<(128 * 2048) / 256, 256, 0, stream>>>(x_proj_w, wtp);
  gemm_bf16<<<dim3(1, NROWS / 128), 256, 0, stream>>>(
      x_cb, wtp, xdbl128, (__hip_bfloat16*)nullptr, (__hip_bfloat16*)nullptr, NROWS, 128, 2048);

  // 4) chunked selective scan (3 passes), in-place on x_c (stores y + D*x)
  scan_passA<<<dim3(512, GCH / 4), 256, 0, stream>>>(x_c, xdbl128, dt_proj_w, dt_proj_b, A_log, hend, sumdl);
  scan_passB<<<128, 256, 0, stream>>>(A_log, sumdl, hend, hinit);
  scan_passC<<<dim3(512, GCH / 4), 256, 0, stream>>>(x_c, xdbl128, dt_proj_w, dt_proj_b, A_log, Dp, hinit);

  // 5) gated bf16 = bf16(x_c * gate_bf)
  gate_convert_bf16<<<(NROWS * DIN) / 1024, 256, 0, stream>>>(x_c, gate_bf, gated, NROWS * DIN);

  // 6) out_proj_w -> bf16 transposed [1024][2048]
  transpose_bf16<<<dim3(1024 / 32, 2048 / 32), dim3(32, 8), 0, stream>>>(out_proj_w, wt3, 2048, 1024);

  // 7) out = gated @ out_proj_w (8192x1024, K=2048)
  gemm_bf16<<<dim3(1024 / 128, NROWS / 128), 256, 0, stream>>>(
      gated, wt3, out, (__hip_bfloat16*)nullptr, (__hip_bfloat16*)nullptr, NROWS, 1024, 2048);
}